// Round 1
// baseline (3498.536 us; speedup 1.0000x reference)
//
#include <hip/hip_runtime.h>
#include <hip/hip_bf16.h>

#define B_ 2
#define S_ 2048
#define DM 2048
#define H_ 16
#define DH 128
#define NBLK 32
#define NKEEP 18
#define BH (B_ * H_)

// ---------------- proj: threefry2x32 (partitionable) + erfinv ----------------
__device__ __forceinline__ unsigned rotl32(unsigned x, int r) {
  return (x << r) | (x >> (32 - r));
}

// XLA ErfInv32 (Giles) polynomial
__device__ __forceinline__ float erfinv_f32(float x) {
  float w = -log1pf(-x * x);
  float p;
  if (w < 5.0f) {
    w -= 2.5f;
    p = 2.81022636e-08f;
    p = fmaf(p, w, 3.43273939e-07f);
    p = fmaf(p, w, -3.5233877e-06f);
    p = fmaf(p, w, -4.39150654e-06f);
    p = fmaf(p, w, 0.00021858087f);
    p = fmaf(p, w, -0.00125372503f);
    p = fmaf(p, w, -0.00417768164f);
    p = fmaf(p, w, 0.246640727f);
    p = fmaf(p, w, 1.50140941f);
  } else {
    w = sqrtf(w) - 3.0f;
    p = -0.000200214257f;
    p = fmaf(p, w, 0.000100950558f);
    p = fmaf(p, w, 0.00134934322f);
    p = fmaf(p, w, -0.00367342844f);
    p = fmaf(p, w, 0.00573950773f);
    p = fmaf(p, w, -0.0076224613f);
    p = fmaf(p, w, 0.00943887047f);
    p = fmaf(p, w, 1.00167406f);
    p = fmaf(p, w, 2.83297682f);
  }
  return p * x;
}

__device__ __forceinline__ float bits_to_normal(unsigned b) {
  // JAX uniform: (bits>>9)|1.0f bits, -1 => [0,1); u = max(lo, f*(hi-lo)+lo)
  float f = __uint_as_float((b >> 9) | 0x3f800000u) - 1.0f;
  const float lo = -0.9999999403953552f;   // nextafter(-1,0)
  float u = fmaxf(lo, fmaf(f, 2.0f, lo));  // hi-lo rounds to exactly 2.0f
  return 1.4142135623730951f * erfinv_f32(u);
}

__global__ void proj_kernel(float* __restrict__ proj) {
  int i = blockIdx.x * blockDim.x + threadIdx.x;  // element index 0..4095
  if (i >= 4096) return;
  unsigned k0 = 0u, k1 = 42u;                     // jax.random.key(42)
  unsigned k2 = 0x1BD11BDAu ^ k0 ^ k1;
  // partitionable: counter = (hi=0, lo=i), 32-bit out = x0 ^ x1
  unsigned x0 = 0u, x1 = (unsigned)i;
  x0 += k0; x1 += k1;
#define QR(r) { x0 += x1; x1 = rotl32(x1, r); x1 ^= x0; }
  QR(13) QR(15) QR(26) QR(6)   x0 += k1; x1 += k2 + 1u;
  QR(17) QR(29) QR(16) QR(24)  x0 += k2; x1 += k0 + 2u;
  QR(13) QR(15) QR(26) QR(6)   x0 += k0; x1 += k1 + 3u;
  QR(17) QR(29) QR(16) QR(24)  x0 += k1; x1 += k2 + 4u;
  QR(13) QR(15) QR(26) QR(6)   x0 += k2; x1 += k0 + 5u;
#undef QR
  proj[i] = bits_to_normal(x0 ^ x1) / 5.656854249492381f;  // / sqrt(32)
}

// ---------------- RoPE tables ----------------
__global__ void rope_table_kernel(float* __restrict__ cosb, float* __restrict__ sinb) {
  int s = blockIdx.x;
  int j = threadIdx.x;  // 0..63
  double e = (double)(2 * j) / 128.0;
  double invf = 1.0 / pow(10000.0, e);
  float freq = (float)s * (float)invf;  // match f32 outer-product rounding
  cosb[s * 64 + j] = (float)cos((double)freq);
  sinb[s * 64 + j] = (float)sin((double)freq);
}

// ---------------- GEMM: C = A @ W^T  (128x128 tile, BK=16, 256 thr, 8x8/thr)
// MODE 0: A = plain (M x 2048) row-major; C scattered to (B,H,S,Dh)
// MODE 1: A = gathered from (B,H,S,Dh); C plain row-major (M x 2048)
template <int MODE>
__global__ __launch_bounds__(256) void gemm_kernel(const float* __restrict__ A,
                                                   const float* __restrict__ W,
                                                   float* __restrict__ C) {
  __shared__ float As[16][132];
  __shared__ float Bs[16][132];
  const int t = threadIdx.x;
  const int n0 = blockIdx.x * 128;
  const int m0 = blockIdx.y * 128;
  const int lrow = t >> 1;
  const int lk = (t & 1) * 8;
  const int ty = t >> 4;
  const int tx = t & 15;
  float acc[8][8];
#pragma unroll
  for (int i = 0; i < 8; ++i)
#pragma unroll
    for (int j = 0; j < 8; ++j) acc[i][j] = 0.0f;

  const int m = m0 + lrow;
  const int b = m >> 11, s = m & (S_ - 1);
  const float* wp_base = W + (size_t)(n0 + lrow) * DM;
  const float* ap_base = A + (size_t)m * DM;  // MODE 0

  for (int k0 = 0; k0 < DM; k0 += 16) {
    const float* ap;
    if (MODE == 0) {
      ap = ap_base + k0 + lk;
    } else {
      int kk0 = k0 + lk;
      int h = kk0 >> 7, d = kk0 & 127;
      ap = A + (((size_t)(b * H_ + h) * S_ + s) * DH + d);
    }
    float4 a0 = *(const float4*)ap;
    float4 a1 = *(const float4*)(ap + 4);
    const float* bp = wp_base + k0 + lk;
    float4 b0 = *(const float4*)bp;
    float4 b1 = *(const float4*)(bp + 4);
    As[lk + 0][lrow] = a0.x; As[lk + 1][lrow] = a0.y;
    As[lk + 2][lrow] = a0.z; As[lk + 3][lrow] = a0.w;
    As[lk + 4][lrow] = a1.x; As[lk + 5][lrow] = a1.y;
    As[lk + 6][lrow] = a1.z; As[lk + 7][lrow] = a1.w;
    Bs[lk + 0][lrow] = b0.x; Bs[lk + 1][lrow] = b0.y;
    Bs[lk + 2][lrow] = b0.z; Bs[lk + 3][lrow] = b0.w;
    Bs[lk + 4][lrow] = b1.x; Bs[lk + 5][lrow] = b1.y;
    Bs[lk + 6][lrow] = b1.z; Bs[lk + 7][lrow] = b1.w;
    __syncthreads();
#pragma unroll
    for (int kk = 0; kk < 16; ++kk) {
      float4 av0 = *(const float4*)&As[kk][ty * 8];
      float4 av1 = *(const float4*)&As[kk][ty * 8 + 4];
      float4 bv0 = *(const float4*)&Bs[kk][tx * 8];
      float4 bv1 = *(const float4*)&Bs[kk][tx * 8 + 4];
      float a[8] = {av0.x, av0.y, av0.z, av0.w, av1.x, av1.y, av1.z, av1.w};
      float bb[8] = {bv0.x, bv0.y, bv0.z, bv0.w, bv1.x, bv1.y, bv1.z, bv1.w};
#pragma unroll
      for (int i = 0; i < 8; ++i)
#pragma unroll
        for (int j = 0; j < 8; ++j) acc[i][j] = fmaf(a[i], bb[j], acc[i][j]);
    }
    __syncthreads();
  }
#pragma unroll
  for (int i = 0; i < 8; ++i) {
    int mm = m0 + ty * 8 + i;
#pragma unroll
    for (int j4 = 0; j4 < 2; ++j4) {
      float4 vv;
      vv.x = acc[i][j4 * 4 + 0]; vv.y = acc[i][j4 * 4 + 1];
      vv.z = acc[i][j4 * 4 + 2]; vv.w = acc[i][j4 * 4 + 3];
      if (MODE == 0) {
        int bb2 = mm >> 11, ss = mm & (S_ - 1);
        int h = n0 >> 7;
        float* cp = C + (((size_t)(bb2 * H_ + h) * S_ + ss) * DH + tx * 8 + j4 * 4);
        *(float4*)cp = vv;
      } else {
        float* cp = C + (size_t)mm * DM + n0 + tx * 8 + j4 * 4;
        *(float4*)cp = vv;
      }
    }
  }
}

// ---------------- RMSNorm + RoPE (+gain for q), in place on (B,H,S,Dh) ------
__global__ __launch_bounds__(256) void rmsrope_kernel(float* __restrict__ q,
                                                      float* __restrict__ k,
                                                      const float* __restrict__ cosb,
                                                      const float* __restrict__ sinb,
                                                      const float* __restrict__ qg) {
  int w = threadIdx.x >> 6;
  int lane = threadIdx.x & 63;
  long row = (long)blockIdx.x * 4 + w;  // 0 .. 2*BH*S-1
  bool isq = row < (long)BH * S_;
  float* base = isq ? q : k;
  long r = isq ? row : row - (long)BH * S_;
  float* p = base + r * DH;
  int s = (int)(r & (S_ - 1));
  int h = (int)((r >> 11) & (H_ - 1));
  float x1 = p[lane], x2 = p[lane + 64];
  float ss = fmaf(x1, x1, x2 * x2);
#pragma unroll
  for (int off = 32; off; off >>= 1) ss += __shfl_xor(ss, off);
  float rms = rsqrtf(ss * (1.0f / 128.0f) + 1e-6f);
  float n1 = x1 * rms, n2 = x2 * rms;
  float c = cosb[s * 64 + lane], sn = sinb[s * 64 + lane];
  float o1 = fmaf(n1, c, n2 * sn);
  float o2 = fmaf(-n1, sn, n2 * c);
  if (isq) { float g = qg[h]; o1 *= g; o2 *= g; }
  p[lane] = o1;
  p[lane + 64] = o2;
}

// ---------------- block selection: JL proj, centroids, radii, top-18 --------
__global__ __launch_bounds__(256) void select_kernel(const float* __restrict__ q,
                                                     const float* __restrict__ k,
                                                     const float* __restrict__ proj,
                                                     int* __restrict__ top_idx) {
  __shared__ float ps[128][32];
  __shared__ float meanq[128];
  __shared__ float red[256];
  __shared__ float qp[32];
  __shared__ float kp[64][33];
  __shared__ float cent[33];
  __shared__ float sc[32];
  const int bh = blockIdx.x, t = threadIdx.x;
  for (int i = t; i < 4096; i += 256) ps[i >> 5][i & 31] = proj[i];
  const float* qb = q + (size_t)bh * S_ * DH;
  const float* kb = k + (size_t)bh * S_ * DH;
  {  // mean over S of q
    int d = t & 127, half = t >> 7;
    float sum = 0.0f;
    int s0 = half * 1024;
#pragma unroll 4
    for (int s = s0; s < s0 + 1024; ++s) sum += qb[(size_t)s * DH + d];
    red[t] = sum;
  }
  __syncthreads();
  if (t < 128) meanq[t] = (red[t] + red[t + 128]) * (1.0f / 2048.0f);
  __syncthreads();
  if (t < 32) {
    float sum = 0.0f;
    for (int d = 0; d < 128; ++d) sum = fmaf(meanq[d], ps[d][t], sum);
    qp[t] = sum;
  }
  __syncthreads();
  if (t == 0) {
    float sum = 0.0f;
    for (int j = 0; j < 32; ++j) sum += qp[j] * qp[j];
    red[0] = 1.0f / fmaxf(sqrtf(sum), 1e-12f);
  }
  __syncthreads();
  if (t < 32) qp[t] *= red[0];
  __syncthreads();

  for (int n = 0; n < NBLK; ++n) {
    const float* kn = kb + (size_t)n * 64 * DH;
    int row = t >> 2, j0 = (t & 3) * 8;
    float accv[8];
#pragma unroll
    for (int jj = 0; jj < 8; ++jj) accv[jj] = 0.0f;
#pragma unroll 4
    for (int d = 0; d < 128; ++d) {
      float kv = kn[(size_t)row * DH + d];
#pragma unroll
      for (int jj = 0; jj < 8; ++jj) accv[jj] = fmaf(kv, ps[d][j0 + jj], accv[jj]);
    }
#pragma unroll
    for (int jj = 0; jj < 8; ++jj) kp[row][j0 + jj] = accv[jj];
    __syncthreads();
    if (t < 64) {  // normalize each row
      float sum = 0.0f;
      for (int j = 0; j < 32; ++j) sum += kp[t][j] * kp[t][j];
      float scl = 1.0f / fmaxf(sqrtf(sum), 1e-12f);
      for (int j = 0; j < 32; ++j) kp[t][j] *= scl;
    }
    __syncthreads();
    if (t < 32) {  // centroid mean
      float sum = 0.0f;
      for (int r2 = 0; r2 < 64; ++r2) sum += kp[r2][t];
      cent[t] = sum * (1.0f / 64.0f);
    }
    __syncthreads();
    if (t == 0) {
      float sum = 0.0f;
      for (int j = 0; j < 32; ++j) sum += cent[j] * cent[j];
      red[0] = 1.0f / fmaxf(sqrtf(sum), 1e-12f);
    }
    __syncthreads();
    if (t < 32) cent[t] *= red[0];
    __syncthreads();
    if (t < 64) {  // radius + score
      float dt = 0.0f;
      for (int j = 0; j < 32; ++j) dt = fmaf(kp[t][j], cent[j], dt);
#pragma unroll
      for (int off = 32; off; off >>= 1) dt = fminf(dt, __shfl_xor(dt, off));
      if (t == 0) {
        float radius = fminf(fmaxf(1.0f - dt, 0.0f), 1.0f);
        float dq = 0.0f;
        for (int j = 0; j < 32; ++j) dq = fmaf(qp[j], cent[j], dq);
        sc[n] = dq + radius;
      }
    }
    __syncthreads();
  }
  if (t == 0) {
    sc[NBLK - 2] = INFINITY;
    sc[NBLK - 1] = INFINITY;
    int chosen[NKEEP];
    bool used[NBLK];
    for (int j = 0; j < NBLK; ++j) used[j] = false;
    for (int kk = 0; kk < NKEEP; ++kk) {
      int best = -1;
      float bv = 0.0f;
      for (int j = 0; j < NBLK; ++j)
        if (!used[j] && (best < 0 || sc[j] > bv)) { bv = sc[j]; best = j; }
      used[best] = true;
      chosen[kk] = best;
    }
    for (int a = 1; a < NKEEP; ++a) {  // sort ascending
      int v2 = chosen[a], b2 = a - 1;
      while (b2 >= 0 && chosen[b2] > v2) { chosen[b2 + 1] = chosen[b2]; --b2; }
      chosen[b2 + 1] = v2;
    }
    for (int a = 0; a < NKEEP; ++a) top_idx[bh * NKEEP + a] = chosen[a];
  }
}

// ---------------- attention over selected blocks (online softmax) -----------
__global__ __launch_bounds__(256) void attn_kernel(const float* __restrict__ q,
                                                   const float* __restrict__ k,
                                                   const float* __restrict__ v,
                                                   const int* __restrict__ top_idx,
                                                   float* __restrict__ y) {
  __shared__ float Ks[32][132];
  __shared__ float Vs[32][132];
  const int bh = blockIdx.x >> 5;
  const int qt = blockIdx.x & 31;
  const int t = threadIdx.x;
  const int r = t >> 2;  // q row in tile (0..63)
  const int c = t & 3;   // dim chunk (32 dims)
  const long qrow = (long)bh * S_ + qt * 64 + r;
  float4 qv[8];
  {
    const float4* src = (const float4*)(q + qrow * DH + c * 32);
#pragma unroll
    for (int i = 0; i < 8; ++i) qv[i] = src[i];
  }
  const int srow = t >> 3;
  const int scol = (t & 7) * 16;
  float m = -INFINITY, lsum = 0.0f;
  float yacc[32];
#pragma unroll
  for (int j = 0; j < 32; ++j) yacc[j] = 0.0f;
  const float scale = 0.08838834764831843f;  // 1/sqrt(128)
  for (int tt = 0; tt < NKEEP * 2; ++tt) {
    int blkid = top_idx[bh * NKEEP + (tt >> 1)];
    long krow0 = (long)bh * S_ + blkid * 64 + (tt & 1) * 32;
    __syncthreads();
    {
      const float4* ks4 = (const float4*)(k + (krow0 + srow) * DH + scol);
      const float4* vs4 = (const float4*)(v + (krow0 + srow) * DH + scol);
      float4* kd = (float4*)&Ks[srow][scol];
      float4* vd = (float4*)&Vs[srow][scol];
#pragma unroll
      for (int i = 0; i < 4; ++i) { kd[i] = ks4[i]; vd[i] = vs4[i]; }
    }
    __syncthreads();
    float lg[32];
#pragma unroll
    for (int key = 0; key < 32; ++key) {
      const float4* kr = (const float4*)&Ks[key][c * 32];
      float pa = 0.0f;
#pragma unroll
      for (int i = 0; i < 8; ++i) {
        float4 kv = kr[i];
        pa = fmaf(qv[i].x, kv.x, pa);
        pa = fmaf(qv[i].y, kv.y, pa);
        pa = fmaf(qv[i].z, kv.z, pa);
        pa = fmaf(qv[i].w, kv.w, pa);
      }
      pa += __shfl_xor(pa, 1);  // quad (c=0..3) reduce -> full 128-dim dot
      pa += __shfl_xor(pa, 2);
      lg[key] = pa * scale;
    }
    float mt = lg[0];
#pragma unroll
    for (int key = 1; key < 32; ++key) mt = fmaxf(mt, lg[key]);
    float mn = fmaxf(m, mt);
    float corr = expf(m - mn);  // first tile: exp(-inf)=0
    lsum *= corr;
#pragma unroll
    for (int j = 0; j < 32; ++j) yacc[j] *= corr;
#pragma unroll
    for (int key = 0; key < 32; ++key) {
      float pp = expf(lg[key] - mn);
      lsum += pp;
      const float* vr = &Vs[key][c * 32];
#pragma unroll
      for (int j = 0; j < 32; ++j) yacc[j] = fmaf(pp, vr[j], yacc[j]);
    }
    m = mn;
  }
  float inv = 1.0f / lsum;
  float* yp = y + qrow * DH + c * 32;
#pragma unroll
  for (int i = 0; i < 8; ++i) {
    float4 vv;
    vv.x = yacc[i * 4 + 0] * inv;
    vv.y = yacc[i * 4 + 1] * inv;
    vv.z = yacc[i * 4 + 2] * inv;
    vv.w = yacc[i * 4 + 3] * inv;
    ((float4*)yp)[i] = vv;
  }
}

extern "C" void kernel_launch(void* const* d_in, const int* in_sizes, int n_in,
                              void* d_out, int out_size, void* d_ws, size_t ws_size,
                              hipStream_t stream) {
  const float* x  = (const float*)d_in[0];
  const float* Wq = (const float*)d_in[1];
  const float* Wk = (const float*)d_in[2];
  const float* Wv = (const float*)d_in[3];
  const float* Wo = (const float*)d_in[4];
  const float* qg = (const float*)d_in[5];
  float* out = (float*)d_out;
  float* ws = (float*)d_ws;

  const size_t NE = (size_t)BH * S_ * DH;  // 8388608
  float* q_ws  = ws;
  float* k_ws  = q_ws + NE;
  float* v_ws  = k_ws + NE;
  float* y_ws  = v_ws + NE;
  float* cosb  = y_ws + NE;
  float* sinb  = cosb + (size_t)S_ * 64;
  float* projb = sinb + (size_t)S_ * 64;
  int*   idxb  = (int*)(projb + 4096);
  // total ws use: ~135.3 MB

  proj_kernel<<<dim3(16), dim3(256), 0, stream>>>(projb);
  rope_table_kernel<<<dim3(S_), dim3(64), 0, stream>>>(cosb, sinb);
  gemm_kernel<0><<<dim3(16, 32), dim3(256), 0, stream>>>(x, Wq, q_ws);
  gemm_kernel<0><<<dim3(16, 32), dim3(256), 0, stream>>>(x, Wk, k_ws);
  gemm_kernel<0><<<dim3(16, 32), dim3(256), 0, stream>>>(x, Wv, v_ws);
  rmsrope_kernel<<<dim3((2 * BH * S_) / 4), dim3(256), 0, stream>>>(q_ws, k_ws, cosb, sinb, qg);
  select_kernel<<<dim3(BH), dim3(256), 0, stream>>>(q_ws, k_ws, projb, idxb);
  attn_kernel<<<dim3(BH * 32), dim3(256), 0, stream>>>(q_ws, k_ws, v_ws, idxb, y_ws);
  gemm_kernel<1><<<dim3(16, 32), dim3(256), 0, stream>>>(y_ws, Wo, out);
}

// Round 2
// 1668.363 us; speedup vs baseline: 2.0970x; 2.0970x over previous
//
#include <hip/hip_runtime.h>
#include <hip/hip_bf16.h>

#define B_ 2
#define S_ 2048
#define DM 2048
#define H_ 16
#define DH 128
#define NBLK 32
#define NKEEP 18
#define BH (B_ * H_)

typedef __attribute__((ext_vector_type(8))) short short8;
typedef __attribute__((ext_vector_type(4))) float f32x4;

#define GLOAD16(gp, lp)                                                        \
  __builtin_amdgcn_global_load_lds(                                            \
      (const __attribute__((address_space(1))) unsigned int*)(const void*)(gp),\
      (__attribute__((address_space(3))) unsigned int*)(void*)(lp), 16, 0, 0)

__device__ __forceinline__ unsigned short f32_to_bf16(float f) {
  unsigned u = __float_as_uint(f);
  unsigned r = (u + 0x7fffu + ((u >> 16) & 1u)) >> 16;
  return (unsigned short)r;
}
__device__ __forceinline__ float bf16_to_f32(unsigned short h) {
  return __uint_as_float(((unsigned)h) << 16);
}

// ---------------- proj: threefry2x32 (partitionable) + erfinv ----------------
__device__ __forceinline__ unsigned rotl32(unsigned x, int r) {
  return (x << r) | (x >> (32 - r));
}

__device__ __forceinline__ float erfinv_f32(float x) {
  float w = -log1pf(-x * x);
  float p;
  if (w < 5.0f) {
    w -= 2.5f;
    p = 2.81022636e-08f;
    p = fmaf(p, w, 3.43273939e-07f);
    p = fmaf(p, w, -3.5233877e-06f);
    p = fmaf(p, w, -4.39150654e-06f);
    p = fmaf(p, w, 0.00021858087f);
    p = fmaf(p, w, -0.00125372503f);
    p = fmaf(p, w, -0.00417768164f);
    p = fmaf(p, w, 0.246640727f);
    p = fmaf(p, w, 1.50140941f);
  } else {
    w = sqrtf(w) - 3.0f;
    p = -0.000200214257f;
    p = fmaf(p, w, 0.000100950558f);
    p = fmaf(p, w, 0.00134934322f);
    p = fmaf(p, w, -0.00367342844f);
    p = fmaf(p, w, 0.00573950773f);
    p = fmaf(p, w, -0.0076224613f);
    p = fmaf(p, w, 0.00943887047f);
    p = fmaf(p, w, 1.00167406f);
    p = fmaf(p, w, 2.83297682f);
  }
  return p * x;
}

__device__ __forceinline__ float bits_to_normal(unsigned b) {
  float f = __uint_as_float((b >> 9) | 0x3f800000u) - 1.0f;
  const float lo = -0.9999999403953552f;
  float u = fmaxf(lo, fmaf(f, 2.0f, lo));
  return 1.4142135623730951f * erfinv_f32(u);
}

__global__ void proj_kernel(float* __restrict__ proj) {
  int i = blockIdx.x * blockDim.x + threadIdx.x;
  if (i >= 4096) return;
  unsigned k0 = 0u, k1 = 42u;
  unsigned k2 = 0x1BD11BDAu ^ k0 ^ k1;
  unsigned x0 = 0u, x1 = (unsigned)i;
  x0 += k0; x1 += k1;
#define QR(r) { x0 += x1; x1 = rotl32(x1, r); x1 ^= x0; }
  QR(13) QR(15) QR(26) QR(6)   x0 += k1; x1 += k2 + 1u;
  QR(17) QR(29) QR(16) QR(24)  x0 += k2; x1 += k0 + 2u;
  QR(13) QR(15) QR(26) QR(6)   x0 += k0; x1 += k1 + 3u;
  QR(17) QR(29) QR(16) QR(24)  x0 += k1; x1 += k2 + 4u;
  QR(13) QR(15) QR(26) QR(6)   x0 += k2; x1 += k0 + 5u;
#undef QR
  proj[i] = bits_to_normal(x0 ^ x1) / 5.656854249492381f;
}

// ---------------- RoPE tables ----------------
__global__ void rope_table_kernel(float* __restrict__ cosb, float* __restrict__ sinb) {
  int s = blockIdx.x;
  int j = threadIdx.x;
  double e = (double)(2 * j) / 128.0;
  double invf = 1.0 / pow(10000.0, e);
  float freq = (float)s * (float)invf;
  cosb[s * 64 + j] = (float)cos((double)freq);
  sinb[s * 64 + j] = (float)sin((double)freq);
}

// ---------------- f32 -> bf16 hi/lo split ----------------
__global__ __launch_bounds__(256) void split_kernel(const float* __restrict__ in,
                                                    unsigned short* __restrict__ hi,
                                                    unsigned short* __restrict__ lo,
                                                    int n4) {
  int i = blockIdx.x * blockDim.x + threadIdx.x;
  if (i >= n4) return;
  float4 v = ((const float4*)in)[i];
  ushort4 hv, lv;
  hv.x = f32_to_bf16(v.x); lv.x = f32_to_bf16(v.x - bf16_to_f32(hv.x));
  hv.y = f32_to_bf16(v.y); lv.y = f32_to_bf16(v.y - bf16_to_f32(hv.y));
  hv.z = f32_to_bf16(v.z); lv.z = f32_to_bf16(v.z - bf16_to_f32(hv.z));
  hv.w = f32_to_bf16(v.w); lv.w = f32_to_bf16(v.w - bf16_to_f32(hv.w));
  ((ushort4*)hi)[i] = hv;
  ((ushort4*)lo)[i] = lv;
}

// ---------------- bf16x3 MFMA GEMM: C = A @ W^T ----------------
// A: [4096][2048] (hi/lo bf16), W: [2048][2048] (hi/lo bf16)
// MODE 0: C f32 scattered to (B,H,S,Dh). MODE 1: C f32 row-major [4096][2048].
template <int MODE>
__global__ __launch_bounds__(256) void mfma_gemm(const unsigned short* __restrict__ Ahi,
                                                 const unsigned short* __restrict__ Alo,
                                                 const unsigned short* __restrict__ Whi,
                                                 const unsigned short* __restrict__ Wlo,
                                                 float* __restrict__ C) {
  __shared__ char smem[32768];  // Ahi 0..8K | Alo 8K | Bhi 16K | Blo 24K, frag-linear
  const int t = threadIdx.x;
  const int l = t & 63;
  const int w = t >> 6;
  const int n0 = blockIdx.x * 128;
  const int m0 = blockIdx.y * 128;
  const int wm = w >> 1, wn = w & 1;
  const int lrow = l & 15;
  const int lk8 = (l >> 4) * 8;

  // this wave stages fragments {2w, 2w+1} of each of the 4 tiles
  const unsigned short* gAh = Ahi + (size_t)(m0 + 32 * w + lrow) * DM + lk8;
  const unsigned short* gAl = Alo + (size_t)(m0 + 32 * w + lrow) * DM + lk8;
  const unsigned short* gBh = Whi + (size_t)(n0 + 32 * w + lrow) * DM + lk8;
  const unsigned short* gBl = Wlo + (size_t)(n0 + 32 * w + lrow) * DM + lk8;
  char* lA = smem + w * 2048;

  f32x4 acc[4][4];
#pragma unroll
  for (int i = 0; i < 4; ++i)
#pragma unroll
    for (int j = 0; j < 4; ++j) acc[i][j] = (f32x4){0.f, 0.f, 0.f, 0.f};

  for (int k0 = 0; k0 < DM; k0 += 32) {
    __syncthreads();
    GLOAD16(gAh + k0, lA);
    GLOAD16(gAh + 16 * DM + k0, lA + 1024);
    GLOAD16(gAl + k0, lA + 8192);
    GLOAD16(gAl + 16 * DM + k0, lA + 8192 + 1024);
    GLOAD16(gBh + k0, lA + 16384);
    GLOAD16(gBh + 16 * DM + k0, lA + 16384 + 1024);
    GLOAD16(gBl + k0, lA + 24576);
    GLOAD16(gBl + 16 * DM + k0, lA + 24576 + 1024);
    __syncthreads();
    short8 ah[4], al[4], bh[4], bl[4];
#pragma unroll
    for (int f = 0; f < 4; ++f) {
      ah[f] = *(const short8*)(smem + (wm * 4 + f) * 1024 + l * 16);
      al[f] = *(const short8*)(smem + 8192 + (wm * 4 + f) * 1024 + l * 16);
      bh[f] = *(const short8*)(smem + 16384 + (wn * 4 + f) * 1024 + l * 16);
      bl[f] = *(const short8*)(smem + 24576 + (wn * 4 + f) * 1024 + l * 16);
    }
#pragma unroll
    for (int i = 0; i < 4; ++i)
#pragma unroll
      for (int j = 0; j < 4; ++j) {
        acc[i][j] = __builtin_amdgcn_mfma_f32_16x16x32_bf16(ah[i], bh[j], acc[i][j], 0, 0, 0);
        acc[i][j] = __builtin_amdgcn_mfma_f32_16x16x32_bf16(ah[i], bl[j], acc[i][j], 0, 0, 0);
        acc[i][j] = __builtin_amdgcn_mfma_f32_16x16x32_bf16(al[i], bh[j], acc[i][j], 0, 0, 0);
      }
  }

#pragma unroll
  for (int i = 0; i < 4; ++i) {
    int row0 = m0 + wm * 64 + i * 16 + (l >> 4) * 4;
#pragma unroll
    for (int j = 0; j < 4; ++j) {
      int col = n0 + wn * 64 + j * 16 + (l & 15);
#pragma unroll
      for (int r = 0; r < 4; ++r) {
        int mm = row0 + r;
        if (MODE == 0) {
          int b = mm >> 11, s = mm & (S_ - 1), h = col >> 7, d = col & 127;
          C[(((size_t)(b * H_ + h) * S_) + s) * DH + d] = acc[i][j][r];
        } else {
          C[(size_t)mm * DM + col] = acc[i][j][r];
        }
      }
    }
  }
}

// ---------------- RMSNorm + RoPE (+gain for q), in place on (B,H,S,Dh) ------
__global__ __launch_bounds__(256) void rmsrope_kernel(float* __restrict__ q,
                                                      float* __restrict__ k,
                                                      const float* __restrict__ cosb,
                                                      const float* __restrict__ sinb,
                                                      const float* __restrict__ qg) {
  int w = threadIdx.x >> 6;
  int lane = threadIdx.x & 63;
  long row = (long)blockIdx.x * 4 + w;
  bool isq = row < (long)BH * S_;
  float* base = isq ? q : k;
  long r = isq ? row : row - (long)BH * S_;
  float* p = base + r * DH;
  int s = (int)(r & (S_ - 1));
  int h = (int)((r >> 11) & (H_ - 1));
  float x1 = p[lane], x2 = p[lane + 64];
  float ss = fmaf(x1, x1, x2 * x2);
#pragma unroll
  for (int off = 32; off; off >>= 1) ss += __shfl_xor(ss, off);
  float rms = rsqrtf(ss * (1.0f / 128.0f) + 1e-6f);
  float n1 = x1 * rms, n2 = x2 * rms;
  float c = cosb[s * 64 + lane], sn = sinb[s * 64 + lane];
  float o1 = fmaf(n1, c, n2 * sn);
  float o2 = fmaf(-n1, sn, n2 * c);
  if (isq) { float g = qg[h]; o1 *= g; o2 *= g; }
  p[lane] = o1;
  p[lane + 64] = o2;
}

// ---------------- block selection ----------------
__global__ __launch_bounds__(256) void select_kernel(const float* __restrict__ q,
                                                     const float* __restrict__ k,
                                                     const float* __restrict__ proj,
                                                     int* __restrict__ top_idx) {
  __shared__ float ps[128][32];
  __shared__ float meanq[128];
  __shared__ float red[256];
  __shared__ float qp[32];
  __shared__ float kp[64][33];
  __shared__ float cent[33];
  __shared__ float sc[32];
  const int bh = blockIdx.x, t = threadIdx.x;
  for (int i = t; i < 4096; i += 256) ps[i >> 5][i & 31] = proj[i];
  const float* qb = q + (size_t)bh * S_ * DH;
  const float* kb = k + (size_t)bh * S_ * DH;
  {
    int d = t & 127, half = t >> 7;
    float sum = 0.0f;
    int s0 = half * 1024;
#pragma unroll 4
    for (int s = s0; s < s0 + 1024; ++s) sum += qb[(size_t)s * DH + d];
    red[t] = sum;
  }
  __syncthreads();
  if (t < 128) meanq[t] = (red[t] + red[t + 128]) * (1.0f / 2048.0f);
  __syncthreads();
  if (t < 32) {
    float sum = 0.0f;
    for (int d = 0; d < 128; ++d) sum = fmaf(meanq[d], ps[d][t], sum);
    qp[t] = sum;
  }
  __syncthreads();
  if (t == 0) {
    float sum = 0.0f;
    for (int j = 0; j < 32; ++j) sum += qp[j] * qp[j];
    red[0] = 1.0f / fmaxf(sqrtf(sum), 1e-12f);
  }
  __syncthreads();
  if (t < 32) qp[t] *= red[0];
  __syncthreads();

  for (int n = 0; n < NBLK; ++n) {
    const float* kn = kb + (size_t)n * 64 * DH;
    int row = t >> 2, j0 = (t & 3) * 8;
    float accv[8];
#pragma unroll
    for (int jj = 0; jj < 8; ++jj) accv[jj] = 0.0f;
#pragma unroll 4
    for (int d = 0; d < 128; ++d) {
      float kv = kn[(size_t)row * DH + d];
#pragma unroll
      for (int jj = 0; jj < 8; ++jj) accv[jj] = fmaf(kv, ps[d][j0 + jj], accv[jj]);
    }
#pragma unroll
    for (int jj = 0; jj < 8; ++jj) kp[row][j0 + jj] = accv[jj];
    __syncthreads();
    if (t < 64) {
      float sum = 0.0f;
      for (int j = 0; j < 32; ++j) sum += kp[t][j] * kp[t][j];
      float scl = 1.0f / fmaxf(sqrtf(sum), 1e-12f);
      for (int j = 0; j < 32; ++j) kp[t][j] *= scl;
    }
    __syncthreads();
    if (t < 32) {
      float sum = 0.0f;
      for (int r2 = 0; r2 < 64; ++r2) sum += kp[r2][t];
      cent[t] = sum * (1.0f / 64.0f);
    }
    __syncthreads();
    if (t == 0) {
      float sum = 0.0f;
      for (int j = 0; j < 32; ++j) sum += cent[j] * cent[j];
      red[0] = 1.0f / fmaxf(sqrtf(sum), 1e-12f);
    }
    __syncthreads();
    if (t < 32) cent[t] *= red[0];
    __syncthreads();
    if (t < 64) {
      float dt = 0.0f;
      for (int j = 0; j < 32; ++j) dt = fmaf(kp[t][j], cent[j], dt);
#pragma unroll
      for (int off = 32; off; off >>= 1) dt = fminf(dt, __shfl_xor(dt, off));
      if (t == 0) {
        float radius = fminf(fmaxf(1.0f - dt, 0.0f), 1.0f);
        float dq = 0.0f;
        for (int j = 0; j < 32; ++j) dq = fmaf(qp[j], cent[j], dq);
        sc[n] = dq + radius;
      }
    }
    __syncthreads();
  }
  if (t == 0) {
    sc[NBLK - 2] = INFINITY;
    sc[NBLK - 1] = INFINITY;
    int chosen[NKEEP];
    bool used[NBLK];
    for (int j = 0; j < NBLK; ++j) used[j] = false;
    for (int kk = 0; kk < NKEEP; ++kk) {
      int best = -1;
      float bv = 0.0f;
      for (int j = 0; j < NBLK; ++j)
        if (!used[j] && (best < 0 || sc[j] > bv)) { bv = sc[j]; best = j; }
      used[best] = true;
      chosen[kk] = best;
    }
    for (int a = 1; a < NKEEP; ++a) {
      int v2 = chosen[a], b2 = a - 1;
      while (b2 >= 0 && chosen[b2] > v2) { chosen[b2 + 1] = chosen[b2]; --b2; }
      chosen[b2 + 1] = v2;
    }
    for (int a = 0; a < NKEEP; ++a) top_idx[bh * NKEEP + a] = chosen[a];
  }
}

// ---------------- attention (gapped LDS layout, writes y as bf16 hi/lo) -----
__global__ __launch_bounds__(256) void attn_kernel(const float* __restrict__ q,
                                                   const float* __restrict__ k,
                                                   const float* __restrict__ v,
                                                   const int* __restrict__ top_idx,
                                                   unsigned short* __restrict__ yhi,
                                                   unsigned short* __restrict__ ylo) {
  // gapped layout: row stride 144 floats; dim-block c (32 floats) at col c*36
  __shared__ float Ks[32][144];
  __shared__ float Vs[32][144];
  const int bh = blockIdx.x >> 5;
  const int qt = blockIdx.x & 31;
  const int t = threadIdx.x;
  const int r = t >> 2;
  const int c = t & 3;
  const long qrow = (long)bh * S_ + qt * 64 + r;
  float4 qv[8];
  {
    const float4* src = (const float4*)(q + qrow * DH + c * 32);
#pragma unroll
    for (int i = 0; i < 8; ++i) qv[i] = src[i];
  }
  const int srow = t >> 3;
  const int scol = (t & 7) * 16;
  const int gcol = (scol >> 5) * 36 + (scol & 31);
  float m = -INFINITY, lsum = 0.0f;
  float yacc[32];
#pragma unroll
  for (int j = 0; j < 32; ++j) yacc[j] = 0.0f;
  const float scale = 0.08838834764831843f;
  for (int tt = 0; tt < NKEEP * 2; ++tt) {
    int blkid = top_idx[bh * NKEEP + (tt >> 1)];
    long krow0 = (long)bh * S_ + blkid * 64 + (tt & 1) * 32;
    __syncthreads();
    {
      const float4* ks4 = (const float4*)(k + (krow0 + srow) * DH + scol);
      const float4* vs4 = (const float4*)(v + (krow0 + srow) * DH + scol);
      float4* kd = (float4*)&Ks[srow][gcol];
      float4* vd = (float4*)&Vs[srow][gcol];
#pragma unroll
      for (int i = 0; i < 4; ++i) { kd[i] = ks4[i]; vd[i] = vs4[i]; }
    }
    __syncthreads();
    float lg[32];
#pragma unroll
    for (int key = 0; key < 32; ++key) {
      const float4* kr = (const float4*)&Ks[key][c * 36];
      float pa = 0.0f;
#pragma unroll
      for (int i = 0; i < 8; ++i) {
        float4 kv = kr[i];
        pa = fmaf(qv[i].x, kv.x, pa);
        pa = fmaf(qv[i].y, kv.y, pa);
        pa = fmaf(qv[i].z, kv.z, pa);
        pa = fmaf(qv[i].w, kv.w, pa);
      }
      pa += __shfl_xor(pa, 1);
      pa += __shfl_xor(pa, 2);
      lg[key] = pa * scale;
    }
    float mt = lg[0];
#pragma unroll
    for (int key = 1; key < 32; ++key) mt = fmaxf(mt, lg[key]);
    float mn = fmaxf(m, mt);
    float corr = __expf(m - mn);
    lsum *= corr;
#pragma unroll
    for (int j = 0; j < 32; ++j) yacc[j] *= corr;
#pragma unroll
    for (int key = 0; key < 32; ++key) {
      float pp = __expf(lg[key] - mn);
      lsum += pp;
      const float4* vr4 = (const float4*)&Vs[key][c * 36];
#pragma unroll
      for (int i = 0; i < 8; ++i) {
        float4 vv = vr4[i];
        yacc[i * 4 + 0] = fmaf(pp, vv.x, yacc[i * 4 + 0]);
        yacc[i * 4 + 1] = fmaf(pp, vv.y, yacc[i * 4 + 1]);
        yacc[i * 4 + 2] = fmaf(pp, vv.z, yacc[i * 4 + 2]);
        yacc[i * 4 + 3] = fmaf(pp, vv.w, yacc[i * 4 + 3]);
      }
    }
    m = mn;
  }
  float inv = 1.0f / lsum;
  // write y row-major (B,S,Dm) as bf16 hi/lo
  int b = bh >> 4, h = bh & (H_ - 1);
  int s = qt * 64 + r;
  size_t off = (((size_t)b * S_ + s) * DM) + h * DH + c * 32;
#pragma unroll
  for (int i = 0; i < 8; ++i) {
    ushort4 hv, lv;
    float y0 = yacc[i * 4 + 0] * inv;
    float y1 = yacc[i * 4 + 1] * inv;
    float y2 = yacc[i * 4 + 2] * inv;
    float y3 = yacc[i * 4 + 3] * inv;
    hv.x = f32_to_bf16(y0); lv.x = f32_to_bf16(y0 - bf16_to_f32(hv.x));
    hv.y = f32_to_bf16(y1); lv.y = f32_to_bf16(y1 - bf16_to_f32(hv.y));
    hv.z = f32_to_bf16(y2); lv.z = f32_to_bf16(y2 - bf16_to_f32(hv.z));
    hv.w = f32_to_bf16(y3); lv.w = f32_to_bf16(y3 - bf16_to_f32(hv.w));
    *(ushort4*)&yhi[off + i * 4] = hv;
    *(ushort4*)&ylo[off + i * 4] = lv;
  }
}

extern "C" void kernel_launch(void* const* d_in, const int* in_sizes, int n_in,
                              void* d_out, int out_size, void* d_ws, size_t ws_size,
                              hipStream_t stream) {
  const float* x  = (const float*)d_in[0];
  const float* Wq = (const float*)d_in[1];
  const float* Wk = (const float*)d_in[2];
  const float* Wv = (const float*)d_in[3];
  const float* Wo = (const float*)d_in[4];
  const float* qg = (const float*)d_in[5];
  float* out = (float*)d_out;

  const size_t NE = (size_t)BH * S_ * DH;  // 8388608 elements
  char* p = (char*)d_ws;
  float* q_ws = (float*)p; p += NE * 4;
  float* k_ws = (float*)p; p += NE * 4;
  float* v_ws = (float*)p; p += NE * 4;
  unsigned short* xhi = (unsigned short*)p; p += NE * 2;  // reused as yhi
  unsigned short* xlo = (unsigned short*)p; p += NE * 2;  // reused as ylo
  unsigned short* whi = (unsigned short*)p; p += (size_t)DM * DM * 2;
  unsigned short* wlo = (unsigned short*)p; p += (size_t)DM * DM * 2;
  float* cosb = (float*)p; p += (size_t)S_ * 64 * 4;
  float* sinb = (float*)p; p += (size_t)S_ * 64 * 4;
  float* projb = (float*)p; p += 4096 * 4;
  int* idxb = (int*)p;
  // total ws use ≈ 152 MB

  const int nx4 = (int)(NE / 4);           // x/y split quads
  const int nw4 = (int)((size_t)DM * DM / 4);

  proj_kernel<<<dim3(16), dim3(256), 0, stream>>>(projb);
  rope_table_kernel<<<dim3(S_), dim3(64), 0, stream>>>(cosb, sinb);
  split_kernel<<<dim3(nx4 / 256), dim3(256), 0, stream>>>(x, xhi, xlo, nx4);

  split_kernel<<<dim3(nw4 / 256), dim3(256), 0, stream>>>(Wq, whi, wlo, nw4);
  mfma_gemm<0><<<dim3(16, 32), dim3(256), 0, stream>>>(xhi, xlo, whi, wlo, q_ws);
  split_kernel<<<dim3(nw4 / 256), dim3(256), 0, stream>>>(Wk, whi, wlo, nw4);
  mfma_gemm<0><<<dim3(16, 32), dim3(256), 0, stream>>>(xhi, xlo, whi, wlo, k_ws);
  split_kernel<<<dim3(nw4 / 256), dim3(256), 0, stream>>>(Wv, whi, wlo, nw4);
  mfma_gemm<0><<<dim3(16, 32), dim3(256), 0, stream>>>(xhi, xlo, whi, wlo, v_ws);

  rmsrope_kernel<<<dim3((2 * BH * S_) / 4), dim3(256), 0, stream>>>(q_ws, k_ws, cosb, sinb, qg);
  select_kernel<<<dim3(BH), dim3(256), 0, stream>>>(q_ws, k_ws, projb, idxb);
  attn_kernel<<<dim3(BH * 32), dim3(256), 0, stream>>>(q_ws, k_ws, v_ws, idxb, xhi, xlo);

  split_kernel<<<dim3(nw4 / 256), dim3(256), 0, stream>>>(Wo, whi, wlo, nw4);
  mfma_gemm<1><<<dim3(16, 32), dim3(256), 0, stream>>>(xhi, xlo, whi, wlo, out);
}

// Round 3
// 1079.077 us; speedup vs baseline: 3.2422x; 1.5461x over previous
//
#include <hip/hip_runtime.h>
#include <hip/hip_bf16.h>

#define B_ 2
#define S_ 2048
#define DM 2048
#define H_ 16
#define DH 128
#define NBLK 32
#define NKEEP 18
#define BH (B_ * H_)

typedef __attribute__((ext_vector_type(8))) short short8;
typedef __attribute__((ext_vector_type(8))) _Float16 f16x8;
typedef __attribute__((ext_vector_type(4))) float f32x4;

#define GLOAD16(gp, lp)                                                        \
  __builtin_amdgcn_global_load_lds(                                            \
      (const __attribute__((address_space(1))) unsigned int*)(const void*)(gp),\
      (__attribute__((address_space(3))) unsigned int*)(void*)(lp), 16, 0, 0)

__device__ __forceinline__ unsigned short f32_to_bf16(float f) {
  unsigned u = __float_as_uint(f);
  unsigned r = (u + 0x7fffu + ((u >> 16) & 1u)) >> 16;
  return (unsigned short)r;
}
__device__ __forceinline__ float bf16_to_f32(unsigned short h) {
  return __uint_as_float(((unsigned)h) << 16);
}

// ---------------- proj: threefry2x32 (partitionable) + erfinv ----------------
__device__ __forceinline__ unsigned rotl32(unsigned x, int r) {
  return (x << r) | (x >> (32 - r));
}

__device__ __forceinline__ float erfinv_f32(float x) {
  float w = -log1pf(-x * x);
  float p;
  if (w < 5.0f) {
    w -= 2.5f;
    p = 2.81022636e-08f;
    p = fmaf(p, w, 3.43273939e-07f);
    p = fmaf(p, w, -3.5233877e-06f);
    p = fmaf(p, w, -4.39150654e-06f);
    p = fmaf(p, w, 0.00021858087f);
    p = fmaf(p, w, -0.00125372503f);
    p = fmaf(p, w, -0.00417768164f);
    p = fmaf(p, w, 0.246640727f);
    p = fmaf(p, w, 1.50140941f);
  } else {
    w = sqrtf(w) - 3.0f;
    p = -0.000200214257f;
    p = fmaf(p, w, 0.000100950558f);
    p = fmaf(p, w, 0.00134934322f);
    p = fmaf(p, w, -0.00367342844f);
    p = fmaf(p, w, 0.00573950773f);
    p = fmaf(p, w, -0.0076224613f);
    p = fmaf(p, w, 0.00943887047f);
    p = fmaf(p, w, 1.00167406f);
    p = fmaf(p, w, 2.83297682f);
  }
  return p * x;
}

__device__ __forceinline__ float bits_to_normal(unsigned b) {
  float f = __uint_as_float((b >> 9) | 0x3f800000u) - 1.0f;
  const float lo = -0.9999999403953552f;
  float u = fmaxf(lo, fmaf(f, 2.0f, lo));
  return 1.4142135623730951f * erfinv_f32(u);
}

__global__ void proj_kernel(float* __restrict__ proj) {
  int i = blockIdx.x * blockDim.x + threadIdx.x;
  if (i >= 4096) return;
  unsigned k0 = 0u, k1 = 42u;
  unsigned k2 = 0x1BD11BDAu ^ k0 ^ k1;
  unsigned x0 = 0u, x1 = (unsigned)i;
  x0 += k0; x1 += k1;
#define QR(r) { x0 += x1; x1 = rotl32(x1, r); x1 ^= x0; }
  QR(13) QR(15) QR(26) QR(6)   x0 += k1; x1 += k2 + 1u;
  QR(17) QR(29) QR(16) QR(24)  x0 += k2; x1 += k0 + 2u;
  QR(13) QR(15) QR(26) QR(6)   x0 += k0; x1 += k1 + 3u;
  QR(17) QR(29) QR(16) QR(24)  x0 += k1; x1 += k2 + 4u;
  QR(13) QR(15) QR(26) QR(6)   x0 += k2; x1 += k0 + 5u;
#undef QR
  proj[i] = bits_to_normal(x0 ^ x1) / 5.656854249492381f;
}

// ---------------- RoPE tables ----------------
__global__ void rope_table_kernel(float* __restrict__ cosb, float* __restrict__ sinb) {
  int s = blockIdx.x;
  int j = threadIdx.x;
  double e = (double)(2 * j) / 128.0;
  double invf = 1.0 / pow(10000.0, e);
  float freq = (float)s * (float)invf;
  cosb[s * 64 + j] = (float)cos((double)freq);
  sinb[s * 64 + j] = (float)sin((double)freq);
}

// ---------------- f32 -> bf16 hi/lo split ----------------
__global__ __launch_bounds__(256) void split_kernel(const float* __restrict__ in,
                                                    unsigned short* __restrict__ hi,
                                                    unsigned short* __restrict__ lo,
                                                    int n4) {
  int i = blockIdx.x * blockDim.x + threadIdx.x;
  if (i >= n4) return;
  float4 v = ((const float4*)in)[i];
  ushort4 hv, lv;
  hv.x = f32_to_bf16(v.x); lv.x = f32_to_bf16(v.x - bf16_to_f32(hv.x));
  hv.y = f32_to_bf16(v.y); lv.y = f32_to_bf16(v.y - bf16_to_f32(hv.y));
  hv.z = f32_to_bf16(v.z); lv.z = f32_to_bf16(v.z - bf16_to_f32(hv.z));
  hv.w = f32_to_bf16(v.w); lv.w = f32_to_bf16(v.w - bf16_to_f32(hv.w));
  ((ushort4*)hi)[i] = hv;
  ((ushort4*)lo)[i] = lv;
}

// ---------------- bf16x3 MFMA GEMM: C = A @ W^T ----------------
template <int MODE>
__global__ __launch_bounds__(256) void mfma_gemm(const unsigned short* __restrict__ Ahi,
                                                 const unsigned short* __restrict__ Alo,
                                                 const unsigned short* __restrict__ Whi,
                                                 const unsigned short* __restrict__ Wlo,
                                                 float* __restrict__ C) {
  __shared__ char smem[32768];
  const int t = threadIdx.x;
  const int l = t & 63;
  const int w = t >> 6;
  const int n0 = blockIdx.x * 128;
  const int m0 = blockIdx.y * 128;
  const int wm = w >> 1, wn = w & 1;
  const int lrow = l & 15;
  const int lk8 = (l >> 4) * 8;

  const unsigned short* gAh = Ahi + (size_t)(m0 + 32 * w + lrow) * DM + lk8;
  const unsigned short* gAl = Alo + (size_t)(m0 + 32 * w + lrow) * DM + lk8;
  const unsigned short* gBh = Whi + (size_t)(n0 + 32 * w + lrow) * DM + lk8;
  const unsigned short* gBl = Wlo + (size_t)(n0 + 32 * w + lrow) * DM + lk8;
  char* lA = smem + w * 2048;

  f32x4 acc[4][4];
#pragma unroll
  for (int i = 0; i < 4; ++i)
#pragma unroll
    for (int j = 0; j < 4; ++j) acc[i][j] = (f32x4){0.f, 0.f, 0.f, 0.f};

  for (int k0 = 0; k0 < DM; k0 += 32) {
    __syncthreads();
    GLOAD16(gAh + k0, lA);
    GLOAD16(gAh + 16 * DM + k0, lA + 1024);
    GLOAD16(gAl + k0, lA + 8192);
    GLOAD16(gAl + 16 * DM + k0, lA + 8192 + 1024);
    GLOAD16(gBh + k0, lA + 16384);
    GLOAD16(gBh + 16 * DM + k0, lA + 16384 + 1024);
    GLOAD16(gBl + k0, lA + 24576);
    GLOAD16(gBl + 16 * DM + k0, lA + 24576 + 1024);
    __syncthreads();
    short8 ah[4], al[4], bh[4], bl[4];
#pragma unroll
    for (int f = 0; f < 4; ++f) {
      ah[f] = *(const short8*)(smem + (wm * 4 + f) * 1024 + l * 16);
      al[f] = *(const short8*)(smem + 8192 + (wm * 4 + f) * 1024 + l * 16);
      bh[f] = *(const short8*)(smem + 16384 + (wn * 4 + f) * 1024 + l * 16);
      bl[f] = *(const short8*)(smem + 24576 + (wn * 4 + f) * 1024 + l * 16);
    }
#pragma unroll
    for (int i = 0; i < 4; ++i)
#pragma unroll
      for (int j = 0; j < 4; ++j) {
        acc[i][j] = __builtin_amdgcn_mfma_f32_16x16x32_bf16(ah[i], bh[j], acc[i][j], 0, 0, 0);
        acc[i][j] = __builtin_amdgcn_mfma_f32_16x16x32_bf16(ah[i], bl[j], acc[i][j], 0, 0, 0);
        acc[i][j] = __builtin_amdgcn_mfma_f32_16x16x32_bf16(al[i], bh[j], acc[i][j], 0, 0, 0);
      }
  }

#pragma unroll
  for (int i = 0; i < 4; ++i) {
    int row0 = m0 + wm * 64 + i * 16 + (l >> 4) * 4;
#pragma unroll
    for (int j = 0; j < 4; ++j) {
      int col = n0 + wn * 64 + j * 16 + (l & 15);
#pragma unroll
      for (int r = 0; r < 4; ++r) {
        int mm = row0 + r;
        if (MODE == 0) {
          int b = mm >> 11, s = mm & (S_ - 1), h = col >> 7, d = col & 127;
          C[(((size_t)(b * H_ + h) * S_) + s) * DH + d] = acc[i][j][r];
        } else {
          C[(size_t)mm * DM + col] = acc[i][j][r];
        }
      }
    }
  }
}

// ---------------- RMSNorm + RoPE (+gain for q), in place ------
__global__ __launch_bounds__(256) void rmsrope_kernel(float* __restrict__ q,
                                                      float* __restrict__ k,
                                                      const float* __restrict__ cosb,
                                                      const float* __restrict__ sinb,
                                                      const float* __restrict__ qg) {
  int w = threadIdx.x >> 6;
  int lane = threadIdx.x & 63;
  long row = (long)blockIdx.x * 4 + w;
  bool isq = row < (long)BH * S_;
  float* base = isq ? q : k;
  long r = isq ? row : row - (long)BH * S_;
  float* p = base + r * DH;
  int s = (int)(r & (S_ - 1));
  int h = (int)((r >> 11) & (H_ - 1));
  float x1 = p[lane], x2 = p[lane + 64];
  float ss = fmaf(x1, x1, x2 * x2);
#pragma unroll
  for (int off = 32; off; off >>= 1) ss += __shfl_xor(ss, off);
  float rms = rsqrtf(ss * (1.0f / 128.0f) + 1e-6f);
  float n1 = x1 * rms, n2 = x2 * rms;
  float c = cosb[s * 64 + lane], sn = sinb[s * 64 + lane];
  float o1 = fmaf(n1, c, n2 * sn);
  float o2 = fmaf(-n1, sn, n2 * c);
  if (isq) { float g = qg[h]; o1 *= g; o2 *= g; }
  p[lane] = o1;
  p[lane + 64] = o2;
}

// ---------------- block selection ----------------
__global__ __launch_bounds__(256) void select_kernel(const float* __restrict__ q,
                                                     const float* __restrict__ k,
                                                     const float* __restrict__ proj,
                                                     int* __restrict__ top_idx) {
  __shared__ float ps[128][32];
  __shared__ float meanq[128];
  __shared__ float red[256];
  __shared__ float qp[32];
  __shared__ float kp[64][33];
  __shared__ float cent[33];
  __shared__ float sc[32];
  const int bh = blockIdx.x, t = threadIdx.x;
  for (int i = t; i < 4096; i += 256) ps[i >> 5][i & 31] = proj[i];
  const float* qb = q + (size_t)bh * S_ * DH;
  const float* kb = k + (size_t)bh * S_ * DH;
  {
    int d = t & 127, half = t >> 7;
    float sum = 0.0f;
    int s0 = half * 1024;
#pragma unroll 4
    for (int s = s0; s < s0 + 1024; ++s) sum += qb[(size_t)s * DH + d];
    red[t] = sum;
  }
  __syncthreads();
  if (t < 128) meanq[t] = (red[t] + red[t + 128]) * (1.0f / 2048.0f);
  __syncthreads();
  if (t < 32) {
    float sum = 0.0f;
    for (int d = 0; d < 128; ++d) sum = fmaf(meanq[d], ps[d][t], sum);
    qp[t] = sum;
  }
  __syncthreads();
  if (t == 0) {
    float sum = 0.0f;
    for (int j = 0; j < 32; ++j) sum += qp[j] * qp[j];
    red[0] = 1.0f / fmaxf(sqrtf(sum), 1e-12f);
  }
  __syncthreads();
  if (t < 32) qp[t] *= red[0];
  __syncthreads();

  for (int n = 0; n < NBLK; ++n) {
    const float* kn = kb + (size_t)n * 64 * DH;
    int row = t >> 2, j0 = (t & 3) * 8;
    float accv[8];
#pragma unroll
    for (int jj = 0; jj < 8; ++jj) accv[jj] = 0.0f;
#pragma unroll 4
    for (int d = 0; d < 128; ++d) {
      float kv = kn[(size_t)row * DH + d];
#pragma unroll
      for (int jj = 0; jj < 8; ++jj) accv[jj] = fmaf(kv, ps[d][j0 + jj], accv[jj]);
    }
#pragma unroll
    for (int jj = 0; jj < 8; ++jj) kp[row][j0 + jj] = accv[jj];
    __syncthreads();
    if (t < 64) {
      float sum = 0.0f;
      for (int j = 0; j < 32; ++j) sum += kp[t][j] * kp[t][j];
      float scl = 1.0f / fmaxf(sqrtf(sum), 1e-12f);
      for (int j = 0; j < 32; ++j) kp[t][j] *= scl;
    }
    __syncthreads();
    if (t < 32) {
      float sum = 0.0f;
      for (int r2 = 0; r2 < 64; ++r2) sum += kp[r2][t];
      cent[t] = sum * (1.0f / 64.0f);
    }
    __syncthreads();
    if (t == 0) {
      float sum = 0.0f;
      for (int j = 0; j < 32; ++j) sum += cent[j] * cent[j];
      red[0] = 1.0f / fmaxf(sqrtf(sum), 1e-12f);
    }
    __syncthreads();
    if (t < 32) cent[t] *= red[0];
    __syncthreads();
    if (t < 64) {
      float dt = 0.0f;
      for (int j = 0; j < 32; ++j) dt = fmaf(kp[t][j], cent[j], dt);
#pragma unroll
      for (int off = 32; off; off >>= 1) dt = fminf(dt, __shfl_xor(dt, off));
      if (t == 0) {
        float radius = fminf(fmaxf(1.0f - dt, 0.0f), 1.0f);
        float dq = 0.0f;
        for (int j = 0; j < 32; ++j) dq = fmaf(qp[j], cent[j], dq);
        sc[n] = dq + radius;
      }
    }
    __syncthreads();
  }
  if (t == 0) {
    sc[NBLK - 2] = INFINITY;
    sc[NBLK - 1] = INFINITY;
    int chosen[NKEEP];
    bool used[NBLK];
    for (int j = 0; j < NBLK; ++j) used[j] = false;
    for (int kk = 0; kk < NKEEP; ++kk) {
      int best = -1;
      float bv = 0.0f;
      for (int j = 0; j < NBLK; ++j)
        if (!used[j] && (best < 0 || sc[j] > bv)) { bv = sc[j]; best = j; }
      used[best] = true;
      chosen[kk] = best;
    }
    for (int a = 1; a < NKEEP; ++a) {
      int v2 = chosen[a], b2 = a - 1;
      while (b2 >= 0 && chosen[b2] > v2) { chosen[b2 + 1] = chosen[b2]; --b2; }
      chosen[b2 + 1] = v2;
    }
    for (int a = 0; a < NKEEP; ++a) top_idx[bh * NKEEP + a] = chosen[a];
  }
}

// ---------------- V (f32, (bh,s,d)) -> V^T (fp16, (bh,d,s)) ----------------
__global__ __launch_bounds__(256) void convertV_kernel(const float* __restrict__ v,
                                                       _Float16* __restrict__ vt) {
  __shared__ float tile[64][132];
  const int bh = blockIdx.x >> 5, st = blockIdx.x & 31;
  const int t = threadIdx.x;
  const float* vb = v + ((size_t)(bh * S_ + st * 64)) * DH;
#pragma unroll
  for (int c = 0; c < 8; ++c) {
    int idx = c * 256 + t;  // 2048 float4s
    int s = idx >> 5, d4 = idx & 31;
    float4 val = *(const float4*)(vb + (size_t)s * DH + d4 * 4);
    *(float4*)&tile[s][d4 * 4] = val;
  }
  __syncthreads();
  const int d = t >> 1, sh = t & 1;
  _Float16* dst = vt + ((size_t)bh * DH + d) * S_ + st * 64 + sh * 32;
#pragma unroll
  for (int c = 0; c < 4; ++c) {
    f16x8 h;
#pragma unroll
    for (int jj = 0; jj < 8; ++jj) h[jj] = (_Float16)tile[sh * 32 + c * 8 + jj][d];
    *(f16x8*)(dst + c * 8) = h;
  }
}

// ---------------- MFMA attention over selected blocks ----------------
// grid = BH*32; block = 256 (4 waves x 16 q-rows). K staged f32->fp16 in LDS,
// V staged via global_load_lds from pre-transposed fp16 V^T, P via per-wave LDS.
__global__ __launch_bounds__(256) void attn_mfma_kernel(const float* __restrict__ q,
                                                        const float* __restrict__ k,
                                                        const _Float16* __restrict__ vt,
                                                        const int* __restrict__ top_idx,
                                                        unsigned short* __restrict__ yhi,
                                                        unsigned short* __restrict__ ylo) {
  __shared__ char lds[41984];  // Kf 0..16K | Vf 16K..32K | P 32K.. (4 x 16 x 144B)
  const int bh = blockIdx.x >> 5;
  const int qt = blockIdx.x & 31;
  const int t = threadIdx.x, l = t & 63, w = t >> 6;
  const int lr = l & 15, lg = l >> 4;
  const float scale = 0.08838834764831843f;  // 1/sqrt(128)

  // Q fragments (A operand): q row = lr, k-dim = dc*32 + lg*8 + j
  f16x8 qf[4];
  {
    const float* qbase = q + ((size_t)(bh * S_ + qt * 64 + w * 16 + lr)) * DH + lg * 8;
#pragma unroll
    for (int dc = 0; dc < 4; ++dc) {
      float4 v0 = *(const float4*)(qbase + dc * 32);
      float4 v1 = *(const float4*)(qbase + dc * 32 + 4);
      f16x8 h;
      h[0] = (_Float16)v0.x; h[1] = (_Float16)v0.y; h[2] = (_Float16)v0.z; h[3] = (_Float16)v0.w;
      h[4] = (_Float16)v1.x; h[5] = (_Float16)v1.y; h[6] = (_Float16)v1.z; h[7] = (_Float16)v1.w;
      qf[dc] = h;
    }
  }

  float m_[4] = {-INFINITY, -INFINITY, -INFINITY, -INFINITY};
  float ls[4] = {0.f, 0.f, 0.f, 0.f};
  f32x4 yacc[8];
#pragma unroll
  for (int dt = 0; dt < 8; ++dt) yacc[dt] = (f32x4){0.f, 0.f, 0.f, 0.f};

  char* Pw = lds + 32768 + w * 2304;  // per-wave P: [16 q][72 fp16] (144B rows)

  for (int it = 0; it < NKEEP; ++it) {
    const int blk = top_idx[bh * NKEEP + it];
    const float* kb = k + ((size_t)(bh * S_ + blk * 64)) * DH;
    const _Float16* vb = vt + (size_t)bh * DH * S_ + blk * 64;
    __syncthreads();
    // stage K fragments (this wave: frags 4w..4w+3); frag = kt*4+dc
#pragma unroll
    for (int f = 0; f < 4; ++f) {
      int frag = w * 4 + f;
      int kt = frag >> 2, dc = frag & 3;
      const float* src = kb + (size_t)(kt * 16 + lr) * DH + dc * 32 + lg * 8;
      float4 v0 = *(const float4*)src;
      float4 v1 = *(const float4*)(src + 4);
      f16x8 h;
      h[0] = (_Float16)v0.x; h[1] = (_Float16)v0.y; h[2] = (_Float16)v0.z; h[3] = (_Float16)v0.w;
      h[4] = (_Float16)v1.x; h[5] = (_Float16)v1.y; h[6] = (_Float16)v1.z; h[7] = (_Float16)v1.w;
      *(f16x8*)(lds + frag * 1024 + l * 16) = h;
    }
    // stage V fragments via global_load_lds; frag = K0*8+dt
#pragma unroll
    for (int f = 0; f < 4; ++f) {
      int frag = w * 4 + f;
      int K0 = frag >> 3, dt = frag & 7;
      GLOAD16(vb + (size_t)(dt * 16 + lr) * S_ + K0 * 32 + lg * 8,
              lds + 16384 + frag * 1024);
    }
    __syncthreads();

    // QK^T: S[16q x 64k]
    f32x4 sacc[4];
#pragma unroll
    for (int kt = 0; kt < 4; ++kt) sacc[kt] = (f32x4){0.f, 0.f, 0.f, 0.f};
#pragma unroll
    for (int kt = 0; kt < 4; ++kt)
#pragma unroll
      for (int dc = 0; dc < 4; ++dc) {
        f16x8 kf = *(const f16x8*)(lds + (kt * 4 + dc) * 1024 + l * 16);
        sacc[kt] = __builtin_amdgcn_mfma_f32_16x16x32_f16(qf[dc], kf, sacc[kt], 0, 0, 0);
      }

    // online softmax (per q-row r; row spread over 16 lanes x 4 kt)
    float p[4][4];
#pragma unroll
    for (int r = 0; r < 4; ++r) {
      float mt = fmaxf(fmaxf(sacc[0][r], sacc[1][r]), fmaxf(sacc[2][r], sacc[3][r])) * scale;
#pragma unroll
      for (int off = 1; off < 16; off <<= 1) mt = fmaxf(mt, __shfl_xor(mt, off));
      float mn = fmaxf(m_[r], mt);
      float corr = __expf(m_[r] - mn);
      float rs = 0.f;
#pragma unroll
      for (int kt = 0; kt < 4; ++kt) {
        p[kt][r] = __expf(fmaf(sacc[kt][r], scale, -mn));
        rs += p[kt][r];
      }
#pragma unroll
      for (int off = 1; off < 16; off <<= 1) rs += __shfl_xor(rs, off);
      ls[r] = ls[r] * corr + rs;
      m_[r] = mn;
#pragma unroll
      for (int dt = 0; dt < 8; ++dt) yacc[dt][r] *= corr;
    }

    // P: C-layout (q = lg*4+r, key = kt*16+lr) -> LDS fp16 [16][72]
#pragma unroll
    for (int kt = 0; kt < 4; ++kt)
#pragma unroll
      for (int r = 0; r < 4; ++r)
        *(_Float16*)(Pw + (lg * 4 + r) * 144 + (kt * 16 + lr) * 2) = (_Float16)p[kt][r];

    // PV: Y[16q x 128d] += P[16q x 64k] * V[64k x 128d]
#pragma unroll
    for (int K0 = 0; K0 < 2; ++K0) {
      f16x8 pa = *(const f16x8*)(Pw + lr * 144 + K0 * 64 + lg * 16);
#pragma unroll
      for (int dt = 0; dt < 8; ++dt) {
        f16x8 vf = *(const f16x8*)(lds + 16384 + (K0 * 8 + dt) * 1024 + l * 16);
        yacc[dt] = __builtin_amdgcn_mfma_f32_16x16x32_f16(pa, vf, yacc[dt], 0, 0, 0);
      }
    }
  }

  // epilogue: y / lsum -> bf16 hi/lo, scatter to (B, S, Dm)
  const int b = bh >> 4, h = bh & (H_ - 1);
  float inv[4];
#pragma unroll
  for (int r = 0; r < 4; ++r) inv[r] = 1.0f / ls[r];
#pragma unroll
  for (int r = 0; r < 4; ++r) {
    int srow = qt * 64 + w * 16 + lg * 4 + r;
    size_t off0 = ((size_t)b * S_ + srow) * DM + h * DH + lr;
#pragma unroll
    for (int dt = 0; dt < 8; ++dt) {
      float yv = yacc[dt][r] * inv[r];
      unsigned short hv = f32_to_bf16(yv);
      unsigned short lv = f32_to_bf16(yv - bf16_to_f32(hv));
      yhi[off0 + dt * 16] = hv;
      ylo[off0 + dt * 16] = lv;
    }
  }
}

extern "C" void kernel_launch(void* const* d_in, const int* in_sizes, int n_in,
                              void* d_out, int out_size, void* d_ws, size_t ws_size,
                              hipStream_t stream) {
  const float* x  = (const float*)d_in[0];
  const float* Wq = (const float*)d_in[1];
  const float* Wk = (const float*)d_in[2];
  const float* Wv = (const float*)d_in[3];
  const float* Wo = (const float*)d_in[4];
  const float* qg = (const float*)d_in[5];
  float* out = (float*)d_out;

  const size_t NE = (size_t)BH * S_ * DH;  // 8388608 elements
  char* p = (char*)d_ws;
  float* q_ws = (float*)p; p += NE * 4;
  float* k_ws = (float*)p; p += NE * 4;
  float* v_ws = (float*)p; p += NE * 4;
  unsigned short* xhi = (unsigned short*)p; p += NE * 2;  // reused as yhi
  unsigned short* xlo = (unsigned short*)p; p += NE * 2;  // reused as ylo
  unsigned short* whi = (unsigned short*)p; p += (size_t)DM * DM * 2;
  unsigned short* wlo = (unsigned short*)p; p += (size_t)DM * DM * 2;
  float* cosb = (float*)p; p += (size_t)S_ * 64 * 4;
  float* sinb = (float*)p; p += (size_t)S_ * 64 * 4;
  float* projb = (float*)p; p += 4096 * 4;
  int* idxb = (int*)p;
  // vt (fp16 V^T, 16.8MB) aliases whi+wlo: dead between V-GEMM and Wo-split
  _Float16* vt = (_Float16*)whi;
  // total ws use ~152 MB

  const int nx4 = (int)(NE / 4);
  const int nw4 = (int)((size_t)DM * DM / 4);

  proj_kernel<<<dim3(16), dim3(256), 0, stream>>>(projb);
  rope_table_kernel<<<dim3(S_), dim3(64), 0, stream>>>(cosb, sinb);
  split_kernel<<<dim3(nx4 / 256), dim3(256), 0, stream>>>(x, xhi, xlo, nx4);

  split_kernel<<<dim3(nw4 / 256), dim3(256), 0, stream>>>(Wq, whi, wlo, nw4);
  mfma_gemm<0><<<dim3(16, 32), dim3(256), 0, stream>>>(xhi, xlo, whi, wlo, q_ws);
  split_kernel<<<dim3(nw4 / 256), dim3(256), 0, stream>>>(Wk, whi, wlo, nw4);
  mfma_gemm<0><<<dim3(16, 32), dim3(256), 0, stream>>>(xhi, xlo, whi, wlo, k_ws);
  split_kernel<<<dim3(nw4 / 256), dim3(256), 0, stream>>>(Wv, whi, wlo, nw4);
  mfma_gemm<0><<<dim3(16, 32), dim3(256), 0, stream>>>(xhi, xlo, whi, wlo, v_ws);

  rmsrope_kernel<<<dim3((2 * BH * S_) / 4), dim3(256), 0, stream>>>(q_ws, k_ws, cosb, sinb, qg);
  select_kernel<<<dim3(BH), dim3(256), 0, stream>>>(q_ws, k_ws, projb, idxb);
  convertV_kernel<<<dim3(BH * 32), dim3(256), 0, stream>>>(v_ws, vt);
  attn_mfma_kernel<<<dim3(BH * 32), dim3(256), 0, stream>>>(q_ws, k_ws, vt, idxb, xhi, xlo);

  split_kernel<<<dim3(nw4 / 256), dim3(256), 0, stream>>>(Wo, whi, wlo, nw4);
  mfma_gemm<1><<<dim3(16, 32), dim3(256), 0, stream>>>(xhi, xlo, whi, wlo, out);
}

// Round 4
// 779.410 us; speedup vs baseline: 4.4887x; 1.3845x over previous
//
#include <hip/hip_runtime.h>
#include <hip/hip_bf16.h>

#define B_ 2
#define S_ 2048
#define DM 2048
#define H_ 16
#define DH 128
#define NBLK 32
#define NKEEP 18
#define BH (B_ * H_)

typedef __attribute__((ext_vector_type(8))) short short8;
typedef __attribute__((ext_vector_type(8))) _Float16 f16x8;
typedef __attribute__((ext_vector_type(4))) float f32x4;

#define GLOAD16(gp, lp)                                                        \
  __builtin_amdgcn_global_load_lds(                                            \
      (const __attribute__((address_space(1))) unsigned int*)(const void*)(gp),\
      (__attribute__((address_space(3))) unsigned int*)(void*)(lp), 16, 0, 0)

__device__ __forceinline__ unsigned short f32_to_bf16(float f) {
  unsigned u = __float_as_uint(f);
  unsigned r = (u + 0x7fffu + ((u >> 16) & 1u)) >> 16;
  return (unsigned short)r;
}
__device__ __forceinline__ float bf16_to_f32(unsigned short h) {
  return __uint_as_float(((unsigned)h) << 16);
}

// ---------------- proj: threefry2x32 (partitionable) + erfinv ----------------
__device__ __forceinline__ unsigned rotl32(unsigned x, int r) {
  return (x << r) | (x >> (32 - r));
}

__device__ __forceinline__ float erfinv_f32(float x) {
  float w = -log1pf(-x * x);
  float p;
  if (w < 5.0f) {
    w -= 2.5f;
    p = 2.81022636e-08f;
    p = fmaf(p, w, 3.43273939e-07f);
    p = fmaf(p, w, -3.5233877e-06f);
    p = fmaf(p, w, -4.39150654e-06f);
    p = fmaf(p, w, 0.00021858087f);
    p = fmaf(p, w, -0.00125372503f);
    p = fmaf(p, w, -0.00417768164f);
    p = fmaf(p, w, 0.246640727f);
    p = fmaf(p, w, 1.50140941f);
  } else {
    w = sqrtf(w) - 3.0f;
    p = -0.000200214257f;
    p = fmaf(p, w, 0.000100950558f);
    p = fmaf(p, w, 0.00134934322f);
    p = fmaf(p, w, -0.00367342844f);
    p = fmaf(p, w, 0.00573950773f);
    p = fmaf(p, w, -0.0076224613f);
    p = fmaf(p, w, 0.00943887047f);
    p = fmaf(p, w, 1.00167406f);
    p = fmaf(p, w, 2.83297682f);
  }
  return p * x;
}

__device__ __forceinline__ float bits_to_normal(unsigned b) {
  float f = __uint_as_float((b >> 9) | 0x3f800000u) - 1.0f;
  const float lo = -0.9999999403953552f;
  float u = fmaxf(lo, fmaf(f, 2.0f, lo));
  return 1.4142135623730951f * erfinv_f32(u);
}

__global__ void proj_kernel(float* __restrict__ proj) {
  int i = blockIdx.x * blockDim.x + threadIdx.x;
  if (i >= 4096) return;
  unsigned k0 = 0u, k1 = 42u;
  unsigned k2 = 0x1BD11BDAu ^ k0 ^ k1;
  unsigned x0 = 0u, x1 = (unsigned)i;
  x0 += k0; x1 += k1;
#define QR(r) { x0 += x1; x1 = rotl32(x1, r); x1 ^= x0; }
  QR(13) QR(15) QR(26) QR(6)   x0 += k1; x1 += k2 + 1u;
  QR(17) QR(29) QR(16) QR(24)  x0 += k2; x1 += k0 + 2u;
  QR(13) QR(15) QR(26) QR(6)   x0 += k0; x1 += k1 + 3u;
  QR(17) QR(29) QR(16) QR(24)  x0 += k1; x1 += k2 + 4u;
  QR(13) QR(15) QR(26) QR(6)   x0 += k2; x1 += k0 + 5u;
#undef QR
  proj[i] = bits_to_normal(x0 ^ x1) / 5.656854249492381f;
}

// ---------------- RoPE tables ----------------
__global__ void rope_table_kernel(float* __restrict__ cosb, float* __restrict__ sinb) {
  int s = blockIdx.x;
  int j = threadIdx.x;
  double e = (double)(2 * j) / 128.0;
  double invf = 1.0 / pow(10000.0, e);
  float freq = (float)s * (float)invf;
  cosb[s * 64 + j] = (float)cos((double)freq);
  sinb[s * 64 + j] = (float)sin((double)freq);
}

// ---------------- f32 -> bf16 hi/lo split ----------------
__global__ __launch_bounds__(256) void split_kernel(const float* __restrict__ in,
                                                    unsigned short* __restrict__ hi,
                                                    unsigned short* __restrict__ lo,
                                                    int n4) {
  int i = blockIdx.x * blockDim.x + threadIdx.x;
  if (i >= n4) return;
  float4 v = ((const float4*)in)[i];
  ushort4 hv, lv;
  hv.x = f32_to_bf16(v.x); lv.x = f32_to_bf16(v.x - bf16_to_f32(hv.x));
  hv.y = f32_to_bf16(v.y); lv.y = f32_to_bf16(v.y - bf16_to_f32(hv.y));
  hv.z = f32_to_bf16(v.z); lv.z = f32_to_bf16(v.z - bf16_to_f32(hv.z));
  hv.w = f32_to_bf16(v.w); lv.w = f32_to_bf16(v.w - bf16_to_f32(hv.w));
  ((ushort4*)hi)[i] = hv;
  ((ushort4*)lo)[i] = lv;
}

// ---------------- bf16x3 MFMA GEMM: C = A @ W^T ----------------
template <int MODE>
__global__ __launch_bounds__(256) void mfma_gemm(const unsigned short* __restrict__ Ahi,
                                                 const unsigned short* __restrict__ Alo,
                                                 const unsigned short* __restrict__ Whi,
                                                 const unsigned short* __restrict__ Wlo,
                                                 float* __restrict__ C) {
  __shared__ char smem[32768];
  const int t = threadIdx.x;
  const int l = t & 63;
  const int w = t >> 6;
  const int n0 = blockIdx.x * 128;
  const int m0 = blockIdx.y * 128;
  const int wm = w >> 1, wn = w & 1;
  const int lrow = l & 15;
  const int lk8 = (l >> 4) * 8;

  const unsigned short* gAh = Ahi + (size_t)(m0 + 32 * w + lrow) * DM + lk8;
  const unsigned short* gAl = Alo + (size_t)(m0 + 32 * w + lrow) * DM + lk8;
  const unsigned short* gBh = Whi + (size_t)(n0 + 32 * w + lrow) * DM + lk8;
  const unsigned short* gBl = Wlo + (size_t)(n0 + 32 * w + lrow) * DM + lk8;
  char* lA = smem + w * 2048;

  f32x4 acc[4][4];
#pragma unroll
  for (int i = 0; i < 4; ++i)
#pragma unroll
    for (int j = 0; j < 4; ++j) acc[i][j] = (f32x4){0.f, 0.f, 0.f, 0.f};

  for (int k0 = 0; k0 < DM; k0 += 32) {
    __syncthreads();
    GLOAD16(gAh + k0, lA);
    GLOAD16(gAh + 16 * DM + k0, lA + 1024);
    GLOAD16(gAl + k0, lA + 8192);
    GLOAD16(gAl + 16 * DM + k0, lA + 8192 + 1024);
    GLOAD16(gBh + k0, lA + 16384);
    GLOAD16(gBh + 16 * DM + k0, lA + 16384 + 1024);
    GLOAD16(gBl + k0, lA + 24576);
    GLOAD16(gBl + 16 * DM + k0, lA + 24576 + 1024);
    __syncthreads();
    short8 ah[4], al[4], bh[4], bl[4];
#pragma unroll
    for (int f = 0; f < 4; ++f) {
      ah[f] = *(const short8*)(smem + (wm * 4 + f) * 1024 + l * 16);
      al[f] = *(const short8*)(smem + 8192 + (wm * 4 + f) * 1024 + l * 16);
      bh[f] = *(const short8*)(smem + 16384 + (wn * 4 + f) * 1024 + l * 16);
      bl[f] = *(const short8*)(smem + 24576 + (wn * 4 + f) * 1024 + l * 16);
    }
#pragma unroll
    for (int i = 0; i < 4; ++i)
#pragma unroll
      for (int j = 0; j < 4; ++j) {
        acc[i][j] = __builtin_amdgcn_mfma_f32_16x16x32_bf16(ah[i], bh[j], acc[i][j], 0, 0, 0);
        acc[i][j] = __builtin_amdgcn_mfma_f32_16x16x32_bf16(ah[i], bl[j], acc[i][j], 0, 0, 0);
        acc[i][j] = __builtin_amdgcn_mfma_f32_16x16x32_bf16(al[i], bh[j], acc[i][j], 0, 0, 0);
      }
  }

#pragma unroll
  for (int i = 0; i < 4; ++i) {
    int row0 = m0 + wm * 64 + i * 16 + (l >> 4) * 4;
#pragma unroll
    for (int j = 0; j < 4; ++j) {
      int col = n0 + wn * 64 + j * 16 + (l & 15);
#pragma unroll
      for (int r = 0; r < 4; ++r) {
        int mm = row0 + r;
        if (MODE == 0) {
          int b = mm >> 11, s = mm & (S_ - 1), h = col >> 7, d = col & 127;
          C[(((size_t)(b * H_ + h) * S_) + s) * DH + d] = acc[i][j][r];
        } else {
          C[(size_t)mm * DM + col] = acc[i][j][r];
        }
      }
    }
  }
}

// ---------------- RMSNorm + RoPE (+gain for q), in place ------
__global__ __launch_bounds__(256) void rmsrope_kernel(float* __restrict__ q,
                                                      float* __restrict__ k,
                                                      const float* __restrict__ cosb,
                                                      const float* __restrict__ sinb,
                                                      const float* __restrict__ qg) {
  int w = threadIdx.x >> 6;
  int lane = threadIdx.x & 63;
  long row = (long)blockIdx.x * 4 + w;
  bool isq = row < (long)BH * S_;
  float* base = isq ? q : k;
  long r = isq ? row : row - (long)BH * S_;
  float* p = base + r * DH;
  int s = (int)(r & (S_ - 1));
  int h = (int)((r >> 11) & (H_ - 1));
  float x1 = p[lane], x2 = p[lane + 64];
  float ss = fmaf(x1, x1, x2 * x2);
#pragma unroll
  for (int off = 32; off; off >>= 1) ss += __shfl_xor(ss, off);
  float rms = rsqrtf(ss * (1.0f / 128.0f) + 1e-6f);
  float n1 = x1 * rms, n2 = x2 * rms;
  float c = cosb[s * 64 + lane], sn = sinb[s * 64 + lane];
  float o1 = fmaf(n1, c, n2 * sn);
  float o2 = fmaf(-n1, sn, n2 * c);
  if (isq) { float g = qg[h]; o1 *= g; o2 *= g; }
  p[lane] = o1;
  p[lane + 64] = o2;
}

// ---------------- selection phase 1: q-mean partial sums ----------------
// grid = BH*16; block 256. Each block sums 128 s-rows -> partial[bidx][128]
__global__ __launch_bounds__(256) void qmean_part_kernel(const float* __restrict__ q,
                                                         float* __restrict__ partial) {
  __shared__ float red[256];
  const int bh = blockIdx.x >> 4, chunk = blockIdx.x & 15;
  const int t = threadIdx.x;
  const int d = t & 127, half = t >> 7;
  const float* qb = q + ((size_t)bh * S_ + chunk * 128 + half * 64) * DH;
  float sum = 0.0f;
#pragma unroll 4
  for (int s = 0; s < 64; ++s) sum += qb[(size_t)s * DH + d];
  red[t] = sum;
  __syncthreads();
  if (t < 128) partial[(size_t)blockIdx.x * 128 + t] = red[t] + red[t + 128];
}

// ---------------- selection phase 2: finish mean, project, normalize --------
// grid = BH; block 128
__global__ void qproj_kernel(const float* __restrict__ partial,
                             const float* __restrict__ proj,
                             float* __restrict__ qp) {
  __shared__ float meanq[128];
  __shared__ float qps[32];
  __shared__ float nrm;
  const int bh = blockIdx.x, t = threadIdx.x;
  float s = 0.0f;
#pragma unroll
  for (int c = 0; c < 16; ++c) s += partial[((size_t)bh * 16 + c) * 128 + t];
  meanq[t] = s * (1.0f / 2048.0f);
  __syncthreads();
  if (t < 32) {
    float sum = 0.0f;
    for (int d = 0; d < 128; ++d) sum = fmaf(meanq[d], proj[d * 32 + t], sum);
    qps[t] = sum;
  }
  __syncthreads();
  if (t == 0) {
    float sum = 0.0f;
    for (int j = 0; j < 32; ++j) sum += qps[j] * qps[j];
    nrm = 1.0f / fmaxf(sqrtf(sum), 1e-12f);
  }
  __syncthreads();
  if (t < 32) qp[bh * 32 + t] = qps[t] * nrm;
}

// ---------------- selection phase 3: per-(bh,block) centroid/radius/score ---
// grid = BH*NBLK; block 256
__global__ __launch_bounds__(256) void kscore_kernel(const float* __restrict__ k,
                                                     const float* __restrict__ proj,
                                                     const float* __restrict__ qp,
                                                     float* __restrict__ scores) {
  __shared__ float ps[128][32];
  __shared__ float kp[64][33];
  __shared__ float cent[33];
  __shared__ float nrm;
  const int bh = blockIdx.x >> 5, n = blockIdx.x & 31;
  const int t = threadIdx.x;
  for (int i = t; i < 4096; i += 256) ps[i >> 5][i & 31] = proj[i];
  const float* kn = k + ((size_t)bh * S_ + n * 64) * DH;
  __syncthreads();
  {
    int row = t >> 2, j0 = (t & 3) * 8;
    float accv[8];
#pragma unroll
    for (int jj = 0; jj < 8; ++jj) accv[jj] = 0.0f;
#pragma unroll 4
    for (int d = 0; d < 128; ++d) {
      float kv = kn[(size_t)row * DH + d];
#pragma unroll
      for (int jj = 0; jj < 8; ++jj) accv[jj] = fmaf(kv, ps[d][j0 + jj], accv[jj]);
    }
#pragma unroll
    for (int jj = 0; jj < 8; ++jj) kp[row][j0 + jj] = accv[jj];
  }
  __syncthreads();
  if (t < 64) {
    float sum = 0.0f;
    for (int j = 0; j < 32; ++j) sum += kp[t][j] * kp[t][j];
    float scl = 1.0f / fmaxf(sqrtf(sum), 1e-12f);
    for (int j = 0; j < 32; ++j) kp[t][j] *= scl;
  }
  __syncthreads();
  if (t < 32) {
    float sum = 0.0f;
    for (int r2 = 0; r2 < 64; ++r2) sum += kp[r2][t];
    cent[t] = sum * (1.0f / 64.0f);
  }
  __syncthreads();
  if (t == 0) {
    float sum = 0.0f;
    for (int j = 0; j < 32; ++j) sum += cent[j] * cent[j];
    nrm = 1.0f / fmaxf(sqrtf(sum), 1e-12f);
  }
  __syncthreads();
  if (t < 32) cent[t] *= nrm;
  __syncthreads();
  if (t < 64) {
    float dt = 0.0f;
    for (int j = 0; j < 32; ++j) dt = fmaf(kp[t][j], cent[j], dt);
#pragma unroll
    for (int off = 32; off; off >>= 1) dt = fminf(dt, __shfl_xor(dt, off));
    if (t == 0) {
      float radius = fminf(fmaxf(1.0f - dt, 0.0f), 1.0f);
      float dq = 0.0f;
      for (int j = 0; j < 32; ++j) dq = fmaf(qp[bh * 32 + j], cent[j], dq);
      scores[bh * 32 + n] = dq + radius;
    }
  }
}

// ---------------- selection phase 4: top-18 + sort ----------------
__global__ void topk_kernel(const float* __restrict__ scores, int* __restrict__ top_idx) {
  if (threadIdx.x != 0) return;
  const int bh = blockIdx.x;
  float sc[NBLK];
  for (int j = 0; j < NBLK; ++j) sc[j] = scores[bh * 32 + j];
  sc[NBLK - 2] = INFINITY;
  sc[NBLK - 1] = INFINITY;
  int chosen[NKEEP];
  bool used[NBLK];
  for (int j = 0; j < NBLK; ++j) used[j] = false;
  for (int kk = 0; kk < NKEEP; ++kk) {
    int best = -1;
    float bv = 0.0f;
    for (int j = 0; j < NBLK; ++j)
      if (!used[j] && (best < 0 || sc[j] > bv)) { bv = sc[j]; best = j; }
    used[best] = true;
    chosen[kk] = best;
  }
  for (int a = 1; a < NKEEP; ++a) {
    int v2 = chosen[a], b2 = a - 1;
    while (b2 >= 0 && chosen[b2] > v2) { chosen[b2 + 1] = chosen[b2]; --b2; }
    chosen[b2 + 1] = v2;
  }
  for (int a = 0; a < NKEEP; ++a) top_idx[bh * NKEEP + a] = chosen[a];
}

// ---------------- V (f32, (bh,s,d)) -> V^T (fp16, (bh,d,s)) ----------------
__global__ __launch_bounds__(256) void convertV_kernel(const float* __restrict__ v,
                                                       _Float16* __restrict__ vt) {
  __shared__ float tile[64][132];
  const int bh = blockIdx.x >> 5, st = blockIdx.x & 31;
  const int t = threadIdx.x;
  const float* vb = v + ((size_t)(bh * S_ + st * 64)) * DH;
#pragma unroll
  for (int c = 0; c < 8; ++c) {
    int idx = c * 256 + t;
    int s = idx >> 5, d4 = idx & 31;
    float4 val = *(const float4*)(vb + (size_t)s * DH + d4 * 4);
    *(float4*)&tile[s][d4 * 4] = val;
  }
  __syncthreads();
  const int d = t >> 1, sh = t & 1;
  _Float16* dst = vt + ((size_t)bh * DH + d) * S_ + st * 64 + sh * 32;
#pragma unroll
  for (int c = 0; c < 4; ++c) {
    f16x8 h;
#pragma unroll
    for (int jj = 0; jj < 8; ++jj) h[jj] = (_Float16)tile[sh * 32 + c * 8 + jj][d];
    *(f16x8*)(dst + c * 8) = h;
  }
}

// ---------------- MFMA attention over selected blocks ----------------
__global__ __launch_bounds__(256) void attn_mfma_kernel(const float* __restrict__ q,
                                                        const float* __restrict__ k,
                                                        const _Float16* __restrict__ vt,
                                                        const int* __restrict__ top_idx,
                                                        unsigned short* __restrict__ yhi,
                                                        unsigned short* __restrict__ ylo) {
  __shared__ char lds[41984];  // Kf 0..16K | Vf 16K..32K | P 32K..
  const int bh = blockIdx.x >> 5;
  const int qt = blockIdx.x & 31;
  const int t = threadIdx.x, l = t & 63, w = t >> 6;
  const int lr = l & 15, lg = l >> 4;
  const float scale = 0.08838834764831843f;

  f16x8 qf[4];
  {
    const float* qbase = q + ((size_t)(bh * S_ + qt * 64 + w * 16 + lr)) * DH + lg * 8;
#pragma unroll
    for (int dc = 0; dc < 4; ++dc) {
      float4 v0 = *(const float4*)(qbase + dc * 32);
      float4 v1 = *(const float4*)(qbase + dc * 32 + 4);
      f16x8 h;
      h[0] = (_Float16)v0.x; h[1] = (_Float16)v0.y; h[2] = (_Float16)v0.z; h[3] = (_Float16)v0.w;
      h[4] = (_Float16)v1.x; h[5] = (_Float16)v1.y; h[6] = (_Float16)v1.z; h[7] = (_Float16)v1.w;
      qf[dc] = h;
    }
  }

  float m_[4] = {-INFINITY, -INFINITY, -INFINITY, -INFINITY};
  float ls[4] = {0.f, 0.f, 0.f, 0.f};
  f32x4 yacc[8];
#pragma unroll
  for (int dt = 0; dt < 8; ++dt) yacc[dt] = (f32x4){0.f, 0.f, 0.f, 0.f};

  char* Pw = lds + 32768 + w * 2304;

  for (int it = 0; it < NKEEP; ++it) {
    const int blk = top_idx[bh * NKEEP + it];
    const float* kb = k + ((size_t)(bh * S_ + blk * 64)) * DH;
    const _Float16* vb = vt + (size_t)bh * DH * S_ + blk * 64;
    __syncthreads();
#pragma unroll
    for (int f = 0; f < 4; ++f) {
      int frag = w * 4 + f;
      int kt = frag >> 2, dc = frag & 3;
      const float* src = kb + (size_t)(kt * 16 + lr) * DH + dc * 32 + lg * 8;
      float4 v0 = *(const float4*)src;
      float4 v1 = *(const float4*)(src + 4);
      f16x8 h;
      h[0] = (_Float16)v0.x; h[1] = (_Float16)v0.y; h[2] = (_Float16)v0.z; h[3] = (_Float16)v0.w;
      h[4] = (_Float16)v1.x; h[5] = (_Float16)v1.y; h[6] = (_Float16)v1.z; h[7] = (_Float16)v1.w;
      *(f16x8*)(lds + frag * 1024 + l * 16) = h;
    }
#pragma unroll
    for (int f = 0; f < 4; ++f) {
      int frag = w * 4 + f;
      int K0 = frag >> 3, dt = frag & 7;
      GLOAD16(vb + (size_t)(dt * 16 + lr) * S_ + K0 * 32 + lg * 8,
              lds + 16384 + frag * 1024);
    }
    __syncthreads();

    f32x4 sacc[4];
#pragma unroll
    for (int kt = 0; kt < 4; ++kt) sacc[kt] = (f32x4){0.f, 0.f, 0.f, 0.f};
#pragma unroll
    for (int kt = 0; kt < 4; ++kt)
#pragma unroll
      for (int dc = 0; dc < 4; ++dc) {
        f16x8 kf = *(const f16x8*)(lds + (kt * 4 + dc) * 1024 + l * 16);
        sacc[kt] = __builtin_amdgcn_mfma_f32_16x16x32_f16(qf[dc], kf, sacc[kt], 0, 0, 0);
      }

    float p[4][4];
#pragma unroll
    for (int r = 0; r < 4; ++r) {
      float mt = fmaxf(fmaxf(sacc[0][r], sacc[1][r]), fmaxf(sacc[2][r], sacc[3][r])) * scale;
#pragma unroll
      for (int off = 1; off < 16; off <<= 1) mt = fmaxf(mt, __shfl_xor(mt, off));
      float mn = fmaxf(m_[r], mt);
      float corr = __expf(m_[r] - mn);
      float rs = 0.f;
#pragma unroll
      for (int kt = 0; kt < 4; ++kt) {
        p[kt][r] = __expf(fmaf(sacc[kt][r], scale, -mn));
        rs += p[kt][r];
      }
#pragma unroll
      for (int off = 1; off < 16; off <<= 1) rs += __shfl_xor(rs, off);
      ls[r] = ls[r] * corr + rs;
      m_[r] = mn;
#pragma unroll
      for (int dt = 0; dt < 8; ++dt) yacc[dt][r] *= corr;
    }

#pragma unroll
    for (int kt = 0; kt < 4; ++kt)
#pragma unroll
      for (int r = 0; r < 4; ++r)
        *(_Float16*)(Pw + (lg * 4 + r) * 144 + (kt * 16 + lr) * 2) = (_Float16)p[kt][r];

#pragma unroll
    for (int K0 = 0; K0 < 2; ++K0) {
      f16x8 pa = *(const f16x8*)(Pw + lr * 144 + K0 * 64 + lg * 16);
#pragma unroll
      for (int dt = 0; dt < 8; ++dt) {
        f16x8 vf = *(const f16x8*)(lds + 16384 + (K0 * 8 + dt) * 1024 + l * 16);
        yacc[dt] = __builtin_amdgcn_mfma_f32_16x16x32_f16(pa, vf, yacc[dt], 0, 0, 0);
      }
    }
  }

  const int b = bh >> 4, h = bh & (H_ - 1);
  float inv[4];
#pragma unroll
  for (int r = 0; r < 4; ++r) inv[r] = 1.0f / ls[r];
#pragma unroll
  for (int r = 0; r < 4; ++r) {
    int srow = qt * 64 + w * 16 + lg * 4 + r;
    size_t off0 = ((size_t)b * S_ + srow) * DM + h * DH + lr;
#pragma unroll
    for (int dt = 0; dt < 8; ++dt) {
      float yv = yacc[dt][r] * inv[r];
      unsigned short hv = f32_to_bf16(yv);
      unsigned short lv = f32_to_bf16(yv - bf16_to_f32(hv));
      yhi[off0 + dt * 16] = hv;
      ylo[off0 + dt * 16] = lv;
    }
  }
}

extern "C" void kernel_launch(void* const* d_in, const int* in_sizes, int n_in,
                              void* d_out, int out_size, void* d_ws, size_t ws_size,
                              hipStream_t stream) {
  const float* x  = (const float*)d_in[0];
  const float* Wq = (const float*)d_in[1];
  const float* Wk = (const float*)d_in[2];
  const float* Wv = (const float*)d_in[3];
  const float* Wo = (const float*)d_in[4];
  const float* qg = (const float*)d_in[5];
  float* out = (float*)d_out;

  const size_t NE = (size_t)BH * S_ * DH;  // 8388608 elements
  char* p = (char*)d_ws;
  float* q_ws = (float*)p; p += NE * 4;
  float* k_ws = (float*)p; p += NE * 4;
  float* v_ws = (float*)p; p += NE * 4;
  unsigned short* xhi = (unsigned short*)p; p += NE * 2;  // reused as yhi
  unsigned short* xlo = (unsigned short*)p; p += NE * 2;  // reused as ylo
  unsigned short* whi = (unsigned short*)p; p += (size_t)DM * DM * 2;
  unsigned short* wlo = (unsigned short*)p; p += (size_t)DM * DM * 2;
  float* cosb = (float*)p; p += (size_t)S_ * 64 * 4;
  float* sinb = (float*)p; p += (size_t)S_ * 64 * 4;
  float* projb = (float*)p; p += 4096 * 4;
  int* idxb = (int*)p; p += BH * NKEEP * 4;
  float* scores = (float*)p; p += BH * NBLK * 4;
  float* qpbuf = (float*)p; p += BH * 32 * 4;
  float* qpart = (float*)p; p += (size_t)BH * 16 * 128 * 4;
  _Float16* vt = (_Float16*)whi;  // aliases whi+wlo (dead between V-GEMM and Wo-split)
  // total ws use ~152 MB

  const int nx4 = (int)(NE / 4);
  const int nw4 = (int)((size_t)DM * DM / 4);

  proj_kernel<<<dim3(16), dim3(256), 0, stream>>>(projb);
  rope_table_kernel<<<dim3(S_), dim3(64), 0, stream>>>(cosb, sinb);
  split_kernel<<<dim3(nx4 / 256), dim3(256), 0, stream>>>(x, xhi, xlo, nx4);

  split_kernel<<<dim3(nw4 / 256), dim3(256), 0, stream>>>(Wq, whi, wlo, nw4);
  mfma_gemm<0><<<dim3(16, 32), dim3(256), 0, stream>>>(xhi, xlo, whi, wlo, q_ws);
  split_kernel<<<dim3(nw4 / 256), dim3(256), 0, stream>>>(Wk, whi, wlo, nw4);
  mfma_gemm<0><<<dim3(16, 32), dim3(256), 0, stream>>>(xhi, xlo, whi, wlo, k_ws);
  split_kernel<<<dim3(nw4 / 256), dim3(256), 0, stream>>>(Wv, whi, wlo, nw4);
  mfma_gemm<0><<<dim3(16, 32), dim3(256), 0, stream>>>(xhi, xlo, whi, wlo, v_ws);

  rmsrope_kernel<<<dim3((2 * BH * S_) / 4), dim3(256), 0, stream>>>(q_ws, k_ws, cosb, sinb, qg);

  qmean_part_kernel<<<dim3(BH * 16), dim3(256), 0, stream>>>(q_ws, qpart);
  qproj_kernel<<<dim3(BH), dim3(128), 0, stream>>>(qpart, projb, qpbuf);
  kscore_kernel<<<dim3(BH * NBLK), dim3(256), 0, stream>>>(k_ws, projb, qpbuf, scores);
  topk_kernel<<<dim3(BH), dim3(64), 0, stream>>>(scores, idxb);

  convertV_kernel<<<dim3(BH * 32), dim3(256), 0, stream>>>(v_ws, vt);
  attn_mfma_kernel<<<dim3(BH * 32), dim3(256), 0, stream>>>(q_ws, k_ws, vt, idxb, xhi, xlo);

  split_kernel<<<dim3(nw4 / 256), dim3(256), 0, stream>>>(Wo, whi, wlo, nw4);
  mfma_gemm<1><<<dim3(16, 32), dim3(256), 0, stream>>>(xhi, xlo, whi, wlo, out);
}

// Round 6
// 590.718 us; speedup vs baseline: 5.9225x; 1.3194x over previous
//
#include <hip/hip_runtime.h>
#include <hip/hip_bf16.h>

#define B_ 2
#define S_ 2048
#define DM 2048
#define H_ 16
#define DH 128
#define NBLK 32
#define NKEEP 18
#define BH (B_ * H_)

typedef __attribute__((ext_vector_type(8))) short short8;
typedef __attribute__((ext_vector_type(8))) _Float16 f16x8;
typedef __attribute__((ext_vector_type(4))) _Float16 f16x4;
typedef __attribute__((ext_vector_type(4))) float f32x4;

#define GLOAD16(gp, lp)                                                        \
  __builtin_amdgcn_global_load_lds(                                            \
      (const __attribute__((address_space(1))) unsigned int*)(const void*)(gp),\
      (__attribute__((address_space(3))) unsigned int*)(void*)(lp), 16, 0, 0)

__device__ __forceinline__ unsigned short f32_to_bf16(float f) {
  unsigned u = __float_as_uint(f);
  unsigned r = (u + 0x7fffu + ((u >> 16) & 1u)) >> 16;
  return (unsigned short)r;
}
__device__ __forceinline__ float bf16_to_f32(unsigned short h) {
  return __uint_as_float(((unsigned)h) << 16);
}

// ---------------- proj: threefry2x32 (partitionable) + erfinv ----------------
__device__ __forceinline__ unsigned rotl32(unsigned x, int r) {
  return (x << r) | (x >> (32 - r));
}

__device__ __forceinline__ float erfinv_f32(float x) {
  float w = -log1pf(-x * x);
  float p;
  if (w < 5.0f) {
    w -= 2.5f;
    p = 2.81022636e-08f;
    p = fmaf(p, w, 3.43273939e-07f);
    p = fmaf(p, w, -3.5233877e-06f);
    p = fmaf(p, w, -4.39150654e-06f);
    p = fmaf(p, w, 0.00021858087f);
    p = fmaf(p, w, -0.00125372503f);
    p = fmaf(p, w, -0.00417768164f);
    p = fmaf(p, w, 0.246640727f);
    p = fmaf(p, w, 1.50140941f);
  } else {
    w = sqrtf(w) - 3.0f;
    p = -0.000200214257f;
    p = fmaf(p, w, 0.000100950558f);
    p = fmaf(p, w, 0.00134934322f);
    p = fmaf(p, w, -0.00367342844f);
    p = fmaf(p, w, 0.00573950773f);
    p = fmaf(p, w, -0.0076224613f);
    p = fmaf(p, w, 0.00943887047f);
    p = fmaf(p, w, 1.00167406f);
    p = fmaf(p, w, 2.83297682f);
  }
  return p * x;
}

__device__ __forceinline__ float bits_to_normal(unsigned b) {
  float f = __uint_as_float((b >> 9) | 0x3f800000u) - 1.0f;
  const float lo = -0.9999999403953552f;
  float u = fmaxf(lo, fmaf(f, 2.0f, lo));
  return 1.4142135623730951f * erfinv_f32(u);
}

__global__ void proj_kernel(float* __restrict__ proj) {
  int i = blockIdx.x * blockDim.x + threadIdx.x;
  if (i >= 4096) return;
  unsigned k0 = 0u, k1 = 42u;
  unsigned k2 = 0x1BD11BDAu ^ k0 ^ k1;
  unsigned x0 = 0u, x1 = (unsigned)i;
  x0 += k0; x1 += k1;
#define QR(r) { x0 += x1; x1 = rotl32(x1, r); x1 ^= x0; }
  QR(13) QR(15) QR(26) QR(6)   x0 += k1; x1 += k2 + 1u;
  QR(17) QR(29) QR(16) QR(24)  x0 += k2; x1 += k0 + 2u;
  QR(13) QR(15) QR(26) QR(6)   x0 += k0; x1 += k1 + 3u;
  QR(17) QR(29) QR(16) QR(24)  x0 += k1; x1 += k2 + 4u;
  QR(13) QR(15) QR(26) QR(6)   x0 += k2; x1 += k0 + 5u;
#undef QR
  proj[i] = bits_to_normal(x0 ^ x1) / 5.656854249492381f;
}

// ---------------- RoPE tables ----------------
__global__ void rope_table_kernel(float* __restrict__ cosb, float* __restrict__ sinb) {
  int s = blockIdx.x;
  int j = threadIdx.x;
  double e = (double)(2 * j) / 128.0;
  double invf = 1.0 / pow(10000.0, e);
  float freq = (float)s * (float)invf;
  cosb[s * 64 + j] = (float)cos((double)freq);
  sinb[s * 64 + j] = (float)sin((double)freq);
}

// ---------------- f32 -> bf16 hi/lo split ----------------
__global__ __launch_bounds__(256) void split_kernel(const float* __restrict__ in,
                                                    unsigned short* __restrict__ hi,
                                                    unsigned short* __restrict__ lo,
                                                    int n4) {
  int i = blockIdx.x * blockDim.x + threadIdx.x;
  if (i >= n4) return;
  float4 v = ((const float4*)in)[i];
  ushort4 hv, lv;
  hv.x = f32_to_bf16(v.x); lv.x = f32_to_bf16(v.x - bf16_to_f32(hv.x));
  hv.y = f32_to_bf16(v.y); lv.y = f32_to_bf16(v.y - bf16_to_f32(hv.y));
  hv.z = f32_to_bf16(v.z); lv.z = f32_to_bf16(v.z - bf16_to_f32(hv.z));
  hv.w = f32_to_bf16(v.w); lv.w = f32_to_bf16(v.w - bf16_to_f32(hv.w));
  ((ushort4*)hi)[i] = hv;
  ((ushort4*)lo)[i] = lv;
}

// ---------------- f32 -> bf16 hi only ----------------
__global__ __launch_bounds__(256) void split_hi_kernel(const float* __restrict__ in,
                                                       unsigned short* __restrict__ hi,
                                                       int n4) {
  int i = blockIdx.x * blockDim.x + threadIdx.x;
  if (i >= n4) return;
  float4 v = ((const float4*)in)[i];
  ushort4 hv;
  hv.x = f32_to_bf16(v.x);
  hv.y = f32_to_bf16(v.y);
  hv.z = f32_to_bf16(v.z);
  hv.w = f32_to_bf16(v.w);
  ((ushort4*)hi)[i] = hv;
}

// ---------------- MFMA GEMM: C = A @ W^T ----------------
// PROD 3: bf16x3 (AhiBhi + AhiBlo + AloBhi). PROD 1: hi-only.
// MODE 0: C f32 scattered to (B,H,S,Dh). MODE 1: C f32 row-major.
// MODE 2: C fp16 transposed to (B*H, Dh, S)  [V^T for attention].
template <int MODE, int PROD>
__global__ __launch_bounds__(256) void mfma_gemm(const unsigned short* __restrict__ Ahi,
                                                 const unsigned short* __restrict__ Alo,
                                                 const unsigned short* __restrict__ Whi,
                                                 const unsigned short* __restrict__ Wlo,
                                                 void* __restrict__ Cout) {
  __shared__ char smem[32768];  // Ahi 0..8K | Alo 8K | Bhi 16K | Blo 24K
  const int t = threadIdx.x;
  const int l = t & 63;
  const int w = t >> 6;
  const int n0 = blockIdx.x * 128;
  const int m0 = blockIdx.y * 128;
  const int wm = w >> 1, wn = w & 1;
  const int lrow = l & 15;
  const int lk8 = (l >> 4) * 8;

  const unsigned short* gAh = Ahi + (size_t)(m0 + 32 * w + lrow) * DM + lk8;
  const unsigned short* gBh = Whi + (size_t)(n0 + 32 * w + lrow) * DM + lk8;
  char* lA = smem + w * 2048;

  f32x4 acc[4][4];
#pragma unroll
  for (int i = 0; i < 4; ++i)
#pragma unroll
    for (int j = 0; j < 4; ++j) acc[i][j] = (f32x4){0.f, 0.f, 0.f, 0.f};

  for (int k0 = 0; k0 < DM; k0 += 32) {
    __syncthreads();
    GLOAD16(gAh + k0, lA);
    GLOAD16(gAh + 16 * DM + k0, lA + 1024);
    GLOAD16(gBh + k0, lA + 16384);
    GLOAD16(gBh + 16 * DM + k0, lA + 16384 + 1024);
    if constexpr (PROD == 3) {
      const unsigned short* gAl = Alo + (size_t)(m0 + 32 * w + lrow) * DM + lk8;
      const unsigned short* gBl = Wlo + (size_t)(n0 + 32 * w + lrow) * DM + lk8;
      GLOAD16(gAl + k0, lA + 8192);
      GLOAD16(gAl + 16 * DM + k0, lA + 8192 + 1024);
      GLOAD16(gBl + k0, lA + 24576);
      GLOAD16(gBl + 16 * DM + k0, lA + 24576 + 1024);
    }
    __syncthreads();
    short8 ah[4], bh[4];
#pragma unroll
    for (int f = 0; f < 4; ++f) {
      ah[f] = *(const short8*)(smem + (wm * 4 + f) * 1024 + l * 16);
      bh[f] = *(const short8*)(smem + 16384 + (wn * 4 + f) * 1024 + l * 16);
    }
    if constexpr (PROD == 3) {
      short8 al[4], bl[4];
#pragma unroll
      for (int f = 0; f < 4; ++f) {
        al[f] = *(const short8*)(smem + 8192 + (wm * 4 + f) * 1024 + l * 16);
        bl[f] = *(const short8*)(smem + 24576 + (wn * 4 + f) * 1024 + l * 16);
      }
#pragma unroll
      for (int i = 0; i < 4; ++i)
#pragma unroll
        for (int j = 0; j < 4; ++j) {
          acc[i][j] = __builtin_amdgcn_mfma_f32_16x16x32_bf16(ah[i], bh[j], acc[i][j], 0, 0, 0);
          acc[i][j] = __builtin_amdgcn_mfma_f32_16x16x32_bf16(ah[i], bl[j], acc[i][j], 0, 0, 0);
          acc[i][j] = __builtin_amdgcn_mfma_f32_16x16x32_bf16(al[i], bh[j], acc[i][j], 0, 0, 0);
        }
    } else {
#pragma unroll
      for (int i = 0; i < 4; ++i)
#pragma unroll
        for (int j = 0; j < 4; ++j)
          acc[i][j] = __builtin_amdgcn_mfma_f32_16x16x32_bf16(ah[i], bh[j], acc[i][j], 0, 0, 0);
    }
  }

#pragma unroll
  for (int i = 0; i < 4; ++i) {
    int row0 = m0 + wm * 64 + i * 16 + (l >> 4) * 4;
#pragma unroll
    for (int j = 0; j < 4; ++j) {
      int col = n0 + wn * 64 + j * 16 + (l & 15);
      if constexpr (MODE == 0) {
        float* C = (float*)Cout;
#pragma unroll
        for (int r = 0; r < 4; ++r) {
          int mm = row0 + r;
          int b = mm >> 11, s = mm & (S_ - 1), h = col >> 7, d = col & 127;
          C[(((size_t)(b * H_ + h) * S_) + s) * DH + d] = acc[i][j][r];
        }
      } else if constexpr (MODE == 1) {
        float* C = (float*)Cout;
#pragma unroll
        for (int r = 0; r < 4; ++r)
          C[(size_t)(row0 + r) * DM + col] = acc[i][j][r];
      } else {  // MODE 2: fp16 V^T (bh, d, s); 4 consecutive s -> 8B store
        _Float16* vtp = (_Float16*)Cout;
        int b = row0 >> 11, s0 = row0 & (S_ - 1);
        int h = col >> 7, d = col & 127;
        f16x4 vv;
        vv[0] = (_Float16)acc[i][j][0];
        vv[1] = (_Float16)acc[i][j][1];
        vv[2] = (_Float16)acc[i][j][2];
        vv[3] = (_Float16)acc[i][j][3];
        *(f16x4*)(vtp + (((size_t)(b * H_ + h)) * DH + d) * S_ + s0) = vv;
      }
    }
  }
}

// ---------------- RMSNorm + RoPE (+gain for q), in place; emits K fp16 ------
__global__ __launch_bounds__(256) void rmsrope_kernel(float* __restrict__ q,
                                                      float* __restrict__ k,
                                                      _Float16* __restrict__ kf,
                                                      const float* __restrict__ cosb,
                                                      const float* __restrict__ sinb,
                                                      const float* __restrict__ qg) {
  int w = threadIdx.x >> 6;
  int lane = threadIdx.x & 63;
  long row = (long)blockIdx.x * 4 + w;
  bool isq = row < (long)BH * S_;
  float* base = isq ? q : k;
  long r = isq ? row : row - (long)BH * S_;
  float* p = base + r * DH;
  int s = (int)(r & (S_ - 1));
  int h = (int)((r >> 11) & (H_ - 1));
  float x1 = p[lane], x2 = p[lane + 64];
  float ss = fmaf(x1, x1, x2 * x2);
#pragma unroll
  for (int off = 32; off; off >>= 1) ss += __shfl_xor(ss, off);
  float rms = rsqrtf(ss * (1.0f / 128.0f) + 1e-6f);
  float n1 = x1 * rms, n2 = x2 * rms;
  float c = cosb[s * 64 + lane], sn = sinb[s * 64 + lane];
  float o1 = fmaf(n1, c, n2 * sn);
  float o2 = fmaf(-n1, sn, n2 * c);
  if (isq) { float g = qg[h]; o1 *= g; o2 *= g; }
  p[lane] = o1;
  p[lane + 64] = o2;
  if (!isq) {
    kf[r * DH + lane] = (_Float16)o1;
    kf[r * DH + lane + 64] = (_Float16)o2;
  }
}

// ---------------- selection phase 1: q-mean partial sums ----------------
__global__ __launch_bounds__(256) void qmean_part_kernel(const float* __restrict__ q,
                                                         float* __restrict__ partial) {
  __shared__ float red[256];
  const int bh = blockIdx.x >> 4, chunk = blockIdx.x & 15;
  const int t = threadIdx.x;
  const int d = t & 127, half = t >> 7;
  const float* qb = q + ((size_t)bh * S_ + chunk * 128 + half * 64) * DH;
  float sum = 0.0f;
#pragma unroll 4
  for (int s = 0; s < 64; ++s) sum += qb[(size_t)s * DH + d];
  red[t] = sum;
  __syncthreads();
  if (t < 128) partial[(size_t)blockIdx.x * 128 + t] = red[t] + red[t + 128];
}

// ---------------- selection phase 2: finish mean, project, normalize --------
__global__ void qproj_kernel(const float* __restrict__ partial,
                             const float* __restrict__ proj,
                             float* __restrict__ qp) {
  __shared__ float meanq[128];
  __shared__ float qps[32];
  __shared__ float nrm;
  const int bh = blockIdx.x, t = threadIdx.x;
  float s = 0.0f;
#pragma unroll
  for (int c = 0; c < 16; ++c) s += partial[((size_t)bh * 16 + c) * 128 + t];
  meanq[t] = s * (1.0f / 2048.0f);
  __syncthreads();
  if (t < 32) {
    float sum = 0.0f;
    for (int d = 0; d < 128; ++d) sum = fmaf(meanq[d], proj[d * 32 + t], sum);
    qps[t] = sum;
  }
  __syncthreads();
  if (t == 0) {
    float sum = 0.0f;
    for (int j = 0; j < 32; ++j) sum += qps[j] * qps[j];
    nrm = 1.0f / fmaxf(sqrtf(sum), 1e-12f);
  }
  __syncthreads();
  if (t < 32) qp[bh * 32 + t] = qps[t] * nrm;
}

// ---------------- selection phase 3: per-(bh,block) score ----------------
__global__ __launch_bounds__(256) void kscore_kernel(const float* __restrict__ k,
                                                     const float* __restrict__ proj,
                                                     const float* __restrict__ qp,
                                                     float* __restrict__ scores) {
  __shared__ float ps[128][32];
  __shared__ float kp[64][33];
  __shared__ float cent[33];
  __shared__ float nrm;
  const int bh = blockIdx.x >> 5, n = blockIdx.x & 31;
  const int t = threadIdx.x;
  for (int i = t; i < 4096; i += 256) ps[i >> 5][i & 31] = proj[i];
  const float* kn = k + ((size_t)bh * S_ + n * 64) * DH;
  __syncthreads();
  {
    int row = t >> 2, j0 = (t & 3) * 8;
    float accv[8];
#pragma unroll
    for (int jj = 0; jj < 8; ++jj) accv[jj] = 0.0f;
#pragma unroll 4
    for (int d = 0; d < 128; ++d) {
      float kv = kn[(size_t)row * DH + d];
#pragma unroll
      for (int jj = 0; jj < 8; ++jj) accv[jj] = fmaf(kv, ps[d][j0 + jj], accv[jj]);
    }
#pragma unroll
    for (int jj = 0; jj < 8; ++jj) kp[row][j0 + jj] = accv[jj];
  }
  __syncthreads();
  if (t < 64) {
    float sum = 0.0f;
    for (int j = 0; j < 32; ++j) sum += kp[t][j] * kp[t][j];
    float scl = 1.0f / fmaxf(sqrtf(sum), 1e-12f);
    for (int j = 0; j < 32; ++j) kp[t][j] *= scl;
  }
  __syncthreads();
  if (t < 32) {
    float sum = 0.0f;
    for (int r2 = 0; r2 < 64; ++r2) sum += kp[r2][t];
    cent[t] = sum * (1.0f / 64.0f);
  }
  __syncthreads();
  if (t == 0) {
    float sum = 0.0f;
    for (int j = 0; j < 32; ++j) sum += cent[j] * cent[j];
    nrm = 1.0f / fmaxf(sqrtf(sum), 1e-12f);
  }
  __syncthreads();
  if (t < 32) cent[t] *= nrm;
  __syncthreads();
  if (t < 64) {
    float dt = 0.0f;
    for (int j = 0; j < 32; ++j) dt = fmaf(kp[t][j], cent[j], dt);
#pragma unroll
    for (int off = 32; off; off >>= 1) dt = fminf(dt, __shfl_xor(dt, off));
    if (t == 0) {
      float radius = fminf(fmaxf(1.0f - dt, 0.0f), 1.0f);
      float dq = 0.0f;
      for (int j = 0; j < 32; ++j) dq = fmaf(qp[bh * 32 + j], cent[j], dq);
      scores[bh * 32 + n] = dq + radius;
    }
  }
}

// ---------------- selection phase 4: top-18 + sort ----------------
__global__ void topk_kernel(const float* __restrict__ scores, int* __restrict__ top_idx) {
  if (threadIdx.x != 0) return;
  const int bh = blockIdx.x;
  float sc[NBLK];
  for (int j = 0; j < NBLK; ++j) sc[j] = scores[bh * 32 + j];
  sc[NBLK - 2] = INFINITY;
  sc[NBLK - 1] = INFINITY;
  int chosen[NKEEP];
  bool used[NBLK];
  for (int j = 0; j < NBLK; ++j) used[j] = false;
  for (int kk = 0; kk < NKEEP; ++kk) {
    int best = -1;
    float bv = 0.0f;
    for (int j = 0; j < NBLK; ++j)
      if (!used[j] && (best < 0 || sc[j] > bv)) { bv = sc[j]; best = j; }
    used[best] = true;
    chosen[kk] = best;
  }
  for (int a = 1; a < NKEEP; ++a) {
    int v2 = chosen[a], b2 = a - 1;
    while (b2 >= 0 && chosen[b2] > v2) { chosen[b2 + 1] = chosen[b2]; --b2; }
    chosen[b2 + 1] = v2;
  }
  for (int a = 0; a < NKEEP; ++a) top_idx[bh * NKEEP + a] = chosen[a];
}

// ---------------- MFMA attention v3: gload_lds staging + double buffer ------
// grid = BH*32; block 256 (4 waves x 16 q rows). K fp16 row-major, V fp16
// transposed; staging = 8 global_load_lds/wave/block, prefetched 1 block ahead.
__global__ __launch_bounds__(256) void attn_mfma_kernel(const float* __restrict__ q,
                                                        const _Float16* __restrict__ kf,
                                                        const _Float16* __restrict__ vt,
                                                        const int* __restrict__ top_idx,
                                                        unsigned short* __restrict__ yhi) {
  __shared__ char lds[74752];  // buf0 0..32K (K 16K | V 16K), buf1 32K..64K, P 64K..
  const int bh = blockIdx.x >> 5;
  const int qt = blockIdx.x & 31;
  const int t = threadIdx.x, l = t & 63, w = t >> 6;
  const int lr = l & 15, lg = l >> 4;
  const float scale = 0.08838834764831843f;  // 1/sqrt(128)

  // Q fragments (A operand): q row = lr, k-dim = dc*32 + lg*8 + j
  f16x8 qf[4];
  {
    const float* qbase = q + ((size_t)(bh * S_ + qt * 64 + w * 16 + lr)) * DH + lg * 8;
#pragma unroll
    for (int dc = 0; dc < 4; ++dc) {
      float4 v0 = *(const float4*)(qbase + dc * 32);
      float4 v1 = *(const float4*)(qbase + dc * 32 + 4);
      f16x8 h;
      h[0] = (_Float16)v0.x; h[1] = (_Float16)v0.y; h[2] = (_Float16)v0.z; h[3] = (_Float16)v0.w;
      h[4] = (_Float16)v1.x; h[5] = (_Float16)v1.y; h[6] = (_Float16)v1.z; h[7] = (_Float16)v1.w;
      qf[dc] = h;
    }
  }

  float m_[4] = {-INFINITY, -INFINITY, -INFINITY, -INFINITY};
  float ls[4] = {0.f, 0.f, 0.f, 0.f};
  f32x4 yacc[8];
#pragma unroll
  for (int dt = 0; dt < 8; ++dt) yacc[dt] = (f32x4){0.f, 0.f, 0.f, 0.f};

  char* Pw = lds + 65536 + w * 2304;  // per-wave P: [16 q][72 fp16]

  const _Float16* kb0 = kf + (size_t)bh * S_ * DH;
  const _Float16* vb0 = vt + (size_t)bh * DH * S_;
  const int* idxp = top_idx + bh * NKEEP;

  // stage K+V fragments of block `blk` into buffer `c` (8 gload_lds per wave)
  auto STAGE = [&](int blk, int c) {
    char* base = lds + c * 32768;
#pragma unroll
    for (int f0 = 0; f0 < 4; ++f0) {
      int f = w * 4 + f0;
      int kt = f >> 2, dc = f & 3;
      GLOAD16(kb0 + (size_t)(blk * 64 + kt * 16 + lr) * DH + dc * 32 + lg * 8,
              base + f * 1024);
      int K0 = f >> 3, dt = f & 7;
      GLOAD16(vb0 + (size_t)(dt * 16 + lr) * S_ + blk * 64 + K0 * 32 + lg * 8,
              base + 16384 + f * 1024);
    }
  };

  int cur = 0;
  STAGE(idxp[0], 0);
  __syncthreads();  // drains vmcnt -> buf0 ready

  for (int it = 0; it < NKEEP; ++it) {
    if (it + 1 < NKEEP) STAGE(idxp[it + 1], cur ^ 1);  // prefetch under compute
    char* buf = lds + cur * 32768;

    // QK^T: S[16q x 64k]
    f32x4 sacc[4];
#pragma unroll
    for (int kt = 0; kt < 4; ++kt) sacc[kt] = (f32x4){0.f, 0.f, 0.f, 0.f};
#pragma unroll
    for (int kt = 0; kt < 4; ++kt)
#pragma unroll
      for (int dc = 0; dc < 4; ++dc) {
        f16x8 kfr = *(const f16x8*)(buf + (kt * 4 + dc) * 1024 + l * 16);
        sacc[kt] = __builtin_amdgcn_mfma_f32_16x16x32_f16(qf[dc], kfr, sacc[kt], 0, 0, 0);
      }

    // online softmax (per q-row r; row spread over 16 lanes x 4 kt)
    float p[4][4];
#pragma unroll
    for (int r = 0; r < 4; ++r) {
      float mt = fmaxf(fmaxf(sacc[0][r], sacc[1][r]), fmaxf(sacc[2][r], sacc[3][r])) * scale;
#pragma unroll
      for (int off = 1; off < 16; off <<= 1) mt = fmaxf(mt, __shfl_xor(mt, off));
      float mn = fmaxf(m_[r], mt);
      float corr = __expf(m_[r] - mn);
      float rs = 0.f;
#pragma unroll
      for (int kt = 0; kt < 4; ++kt) {
        p[kt][r] = __expf(fmaf(sacc[kt][r], scale, -mn));
        rs += p[kt][r];
      }
#pragma unroll
      for (int off = 1; off < 16; off <<= 1) rs += __shfl_xor(rs, off);
      ls[r] = ls[r] * corr + rs;
      m_[r] = mn;
#pragma unroll
      for (int dt = 0; dt < 8; ++dt) yacc[dt][r] *= corr;
    }

    // P: C-layout (q = lg*4+r, key = kt*16+lr) -> per-wave LDS fp16 [16][72]
#pragma unroll
    for (int kt = 0; kt < 4; ++kt)
#pragma unroll
      for (int r = 0; r < 4; ++r)
        *(_Float16*)(Pw + (lg * 4 + r) * 144 + (kt * 16 + lr) * 2) = (_Float16)p[kt][r];

    // PV: Y[16q x 128d] += P[16q x 64k] * V[64k x 128d]
#pragma unroll
    for (int K0 = 0; K0 < 2; ++K0) {
      f16x8 pa = *(const f16x8*)(Pw + lr * 144 + K0 * 64 + lg * 16);
#pragma unroll
      for (int dt = 0; dt < 8; ++dt) {
        f16x8 vf = *(const f16x8*)(buf + 16384 + (K0 * 8 + dt) * 1024 + l * 16);
        yacc[dt] = __builtin_amdgcn_mfma_f32_16x16x32_f16(pa, vf, yacc[dt], 0, 0, 0);
      }
    }

    __syncthreads();  // drains vmcnt (next buf staged) + all LDS reads done
    cur ^= 1;
  }

  // epilogue: y / lsum -> bf16, scatter to (B, S, Dm)
  const int b = bh >> 4, h = bh & (H_ - 1);
  float inv[4];
#pragma unroll
  for (int r = 0; r < 4; ++r) inv[r] = 1.0f / ls[r];
#pragma unroll
  for (int r = 0; r < 4; ++r) {
    int srow = qt * 64 + w * 16 + lg * 4 + r;
    size_t off0 = ((size_t)b * S_ + srow) * DM + h * DH + lr;
#pragma unroll
    for (int dt = 0; dt < 8; ++dt)
      yhi[off0 + dt * 16] = f32_to_bf16(yacc[dt][r] * inv[r]);
  }
}

extern "C" void kernel_launch(void* const* d_in, const int* in_sizes, int n_in,
                              void* d_out, int out_size, void* d_ws, size_t ws_size,
                              hipStream_t stream) {
  const float* x  = (const float*)d_in[0];
  const float* Wq = (const float*)d_in[1];
  const float* Wk = (const float*)d_in[2];
  const float* Wv = (const float*)d_in[3];
  const float* Wo = (const float*)d_in[4];
  const float* qg = (const float*)d_in[5];
  float* out = (float*)d_out;

  const size_t NE = (size_t)BH * S_ * DH;  // 8388608 elements
  char* p = (char*)d_ws;
  float* q_ws = (float*)p; p += NE * 4;
  float* k_ws = (float*)p; p += NE * 4;   // f32 K; REUSED as fp16 V^T after kscore
  _Float16* kf16 = (_Float16*)p; p += NE * 2;
  unsigned short* xhi = (unsigned short*)p; p += NE * 2;  // reused as yhi
  unsigned short* xlo = (unsigned short*)p; p += NE * 2;
  unsigned short* whi = (unsigned short*)p; p += (size_t)DM * DM * 2;
  unsigned short* wlo = (unsigned short*)p; p += (size_t)DM * DM * 2;
  float* cosb = (float*)p; p += (size_t)S_ * 64 * 4;
  float* sinb = (float*)p; p += (size_t)S_ * 64 * 4;
  float* projb = (float*)p; p += 4096 * 4;
  int* idxb = (int*)p; p += BH * NKEEP * 4;
  float* scores = (float*)p; p += BH * NBLK * 4;
  float* qpbuf = (float*)p; p += BH * 32 * 4;
  float* qpart = (float*)p; p += (size_t)BH * 16 * 128 * 4;
  // vt (fp16 V^T, 16.8 MB) lives in the k_ws region (33.6 MB): f32 K is dead
  // after kscore, and the V-GEMM that writes vt launches after topk.
  _Float16* vt = (_Float16*)k_ws;
  // total ws use ~136 MB

  const int nx4 = (int)(NE / 4);
  const int nw4 = (int)((size_t)DM * DM / 4);

  proj_kernel<<<dim3(16), dim3(256), 0, stream>>>(projb);
  rope_table_kernel<<<dim3(S_), dim3(64), 0, stream>>>(cosb, sinb);
  split_kernel<<<dim3(nx4 / 256), dim3(256), 0, stream>>>(x, xhi, xlo, nx4);

  split_kernel<<<dim3(nw4 / 256), dim3(256), 0, stream>>>(Wq, whi, wlo, nw4);
  mfma_gemm<0, 3><<<dim3(16, 32), dim3(256), 0, stream>>>(xhi, xlo, whi, wlo, q_ws);
  split_kernel<<<dim3(nw4 / 256), dim3(256), 0, stream>>>(Wk, whi, wlo, nw4);
  mfma_gemm<0, 3><<<dim3(16, 32), dim3(256), 0, stream>>>(xhi, xlo, whi, wlo, k_ws);

  rmsrope_kernel<<<dim3((2 * BH * S_) / 4), dim3(256), 0, stream>>>(q_ws, k_ws, kf16, cosb, sinb, qg);

  // selection consumes f32 k_ws; must finish before vt overwrites it
  qmean_part_kernel<<<dim3(BH * 16), dim3(256), 0, stream>>>(q_ws, qpart);
  qproj_kernel<<<dim3(BH), dim3(128), 0, stream>>>(qpart, projb, qpbuf);
  kscore_kernel<<<dim3(BH * NBLK), dim3(256), 0, stream>>>(k_ws, projb, qpbuf, scores);
  topk_kernel<<<dim3(BH), dim3(64), 0, stream>>>(scores, idxb);

  // V: hi-only product, writes fp16 V^T directly into vt (= dead k_ws region)
  split_hi_kernel<<<dim3(nw4 / 256), dim3(256), 0, stream>>>(Wv, whi, nw4);
  mfma_gemm<2, 1><<<dim3(16, 32), dim3(256), 0, stream>>>(xhi, nullptr, whi, nullptr, vt);

  attn_mfma_kernel<<<dim3(BH * 32), dim3(256), 0, stream>>>(q_ws, kf16, vt, idxb, xhi);

  // O: hi-only product on yhi (= xhi) and Wo-hi
  split_hi_kernel<<<dim3(nw4 / 256), dim3(256), 0, stream>>>(Wo, whi, nw4);
  mfma_gemm<1, 1><<<dim3(16, 32), dim3(256), 0, stream>>>(xhi, nullptr, whi, nullptr, out);
}